// Round 9
// baseline (1423.512 us; speedup 1.0000x reference)
//
#include <hip/hip_runtime.h>
#include <hip/hip_bf16.h>
#include <cstddef>

#define DEVI __device__ __forceinline__

typedef __attribute__((ext_vector_type(4))) float f4v;
typedef __attribute__((ext_vector_type(16))) float f16v;
typedef __attribute__((ext_vector_type(8))) short s8v;
typedef __attribute__((ext_vector_type(4))) short s4v;

using bf16 = __hip_bfloat16;

// L=8, B=8, N=512, C=1024, H=16, D=64
constexpr float SELU_A = 1.6732632423543772f;
constexpr float SELU_S = 1.0507009873554805f;
constexpr float TPINV  = 0.08838834764831845f; // 1/sqrt(2*D)

DEVI float bfbits(short s) { return __uint_as_float(((unsigned)(unsigned short)s) << 16); }
DEVI unsigned short f2bu(float f) {
  bf16 h = __float2bfloat16(f);
  return __builtin_bit_cast(unsigned short, h);
}
DEVI float seluf(float x) { return x > 0.f ? SELU_S * x : SELU_S * SELU_A * (__expf(x) - 1.f); }

DEVI void gl16(const void* g, void* l) {
  __builtin_amdgcn_global_load_lds((__attribute__((address_space(1))) void*)g,
                                   (__attribute__((address_space(3))) void*)l, 16, 0, 0);
}

DEVI void conv8(const float* __restrict__ src, bf16* __restrict__ dst) {
  f4v a = *(const f4v*)src;
  f4v b = *(const f4v*)(src + 4);
  s8v o;
  #pragma unroll
  for (int j = 0; j < 4; j++) { o[j] = (short)f2bu(a[j]); o[4 + j] = (short)f2bu(b[j]); }
  *(s8v*)dst = o;
}

// ---------------- mask compaction: global 128-aligned packing; t2b at 64-row granularity
__global__ void k_compact(const float* __restrict__ xm, int* __restrict__ idx,
                          int* __restrict__ pos, int* __restrict__ cnt,
                          int* __restrict__ start, int* __restrict__ t2b)
{
  int t = threadIdx.x;           // 512 threads, wave w = batch w
  int b = t >> 6, lane = t & 63;
  __shared__ int scnt[8];
  int base = b * 512 + lane * 8;
  int mb[8]; int lc = 0;
  #pragma unroll
  for (int i = 0; i < 8; i++) { mb[i] = (xm[base + i] != 0.f) ? 1 : 0; lc += mb[i]; }
  int s = lc;
  #pragma unroll
  for (int o = 1; o < 64; o <<= 1) { int tt = __shfl_up(s, o); if (lane >= o) s += tt; }
  int run = s - lc;
  #pragma unroll
  for (int i = 0; i < 8; i++) {
    int n = lane * 8 + i;
    if (mb[i]) { idx[b * 512 + run] = n; pos[b * 512 + n] = run; run++; }
    else pos[b * 512 + n] = -1;
  }
  if (lane == 63) scnt[b] = s;
  __syncthreads();
  if (t == 0) {
    int st = 0, tile = 0;
    for (int bb = 0; bb < 8; bb++) {
      cnt[bb] = scnt[bb];
      start[bb] = st;
      int nt = (scnt[bb] + 127) >> 7;
      for (int k = 0; k < nt * 2; k++) t2b[tile++] = bb;  // 64-row granularity
      st += nt * 128;
    }
    start[8] = st;
    for (; tile < 64; tile++) t2b[tile] = 0;
  }
}

// ---------------- fused prologue: gather | layer-0 weight conv | m6/m2 matvec
__global__ __launch_bounds__(256) void k_prolog(
    const float* __restrict__ xin, const int* __restrict__ idx, const int* __restrict__ cnt,
    const int* __restrict__ start, const int* __restrict__ t2b, float* __restrict__ xc,
    const float* __restrict__ wq, const float* __restrict__ wk, const float* __restrict__ wv,
    const float* __restrict__ w1, const float* __restrict__ w2,
    bf16* __restrict__ wqkvb, bf16* __restrict__ w1b, bf16* __restrict__ w2b,
    const float* __restrict__ cs, const float* __restrict__ Wm, const float* __restrict__ bm,
    float* __restrict__ mAll, const float* __restrict__ Wmf, const float* __restrict__ bmf,
    float* __restrict__ m2v)
{
  int bid = blockIdx.x, t = threadIdx.x;
  __shared__ float cls[8192];
  if (bid < 4096) {
    int row = bid;
    if (row >= start[8]) return;
    int tb = t2b[row >> 6], slot = row - start[tb];
    f4v v = {0.f, 0.f, 0.f, 0.f};
    if (slot < cnt[tb])
      v = *(const f4v*)&xin[((size_t)tb * 512 + idx[tb * 512 + slot]) * 1024 + t * 4];
    *(f4v*)&xc[(size_t)row * 1024 + t * 4] = v;
  } else if (bid < 9728) {
    int i = (bid - 4096) * 256 + t;
    if (i < 393216) {
      int o = i * 8;
      int row = o >> 10, col = o & 1023;
      int sel = row >> 10, sr = row & 1023;
      conv8((sel == 0 ? wq : sel == 1 ? wk : wv) + (size_t)sr * 1024 + col, wqkvb + o);
    } else if (i < 917504) {
      size_t o = (size_t)(i - 393216) * 8;
      conv8(w1 + o, w1b + o);
    } else {
      size_t o = (size_t)(i - 917504) * 8;
      conv8(w2 + o, w2b + o);
    }
  } else {
    int mode = (bid < 22016) ? 0 : 1;
    const float* W = mode ? Wmf : Wm;
    const float* bias = mode ? bmf : bm;
    float* out = mode ? m2v : mAll;
    int O = mode ? 2048 : 49152;
    int ob = mode ? (bid - 22016) : (bid - 9728);
    #pragma unroll
    for (int i = 0; i < 8; i++)
      *(f4v*)&cls[i * 1024 + t * 4] = *(const f4v*)&cs[i * 1024 + t * 4];
    __syncthreads();
    int w = t >> 6, l = t & 63;
    int o = ob * 4 + w;
    if (o >= O) return;
    float acc[8] = {0.f, 0.f, 0.f, 0.f, 0.f, 0.f, 0.f, 0.f};
    const float* Wr = W + (size_t)o * 1024;
    for (int i = 0; i < 16; i++) {
      int k = i * 64 + l;
      float wv2 = Wr[k];
      #pragma unroll
      for (int b = 0; b < 8; b++) acc[b] += wv2 * cls[b * 1024 + k];
    }
    #pragma unroll
    for (int b = 0; b < 8; b++) {
      #pragma unroll
      for (int off = 32; off; off >>= 1) acc[b] += __shfl_xor(acc[b], off);
    }
    float bv = bias[o];
    #pragma unroll
    for (int b = 0; b < 8; b++) {
      if (l == b) {
        float val = acc[b] + bv;
        size_t dst;
        if (mode == 0) { int ll = o / 6144, ft = o - ll * 6144; dst = ((size_t)ll * 8 + b) * 6144 + ft; }
        else dst = (size_t)b * 2048 + o;
        out[dst] = val;
      }
    }
  }
}

// ---------------- scatter final rows back; dead rows = 0
__global__ __launch_bounds__(256) void k_scatter(const float* __restrict__ ffin,
    const int* __restrict__ pos, const int* __restrict__ start, float* __restrict__ out)
{
  int row = blockIdx.x, t = threadIdx.x, b = row >> 9;
  int p = pos[row];
  f4v v = {0.f, 0.f, 0.f, 0.f};
  if (p >= 0) v = *(const f4v*)&ffin[(size_t)(start[b] + p) * 1024 + t * 4];
  *(f4v*)&out[(size_t)row * 1024 + t * 4] = v;
}

// ---------------- conditioning
__global__ void k_cond(const float* __restrict__ tim, const float* __restrict__ lab,
                       const float* __restrict__ Wl, const float* __restrict__ bl,
                       float* __restrict__ cs)
{
  int b = blockIdx.x, t = threadIdx.x;
  float l0 = lab[b * 2 + 0], l1 = lab[b * 2 + 1], tv = tim[b];
  #pragma unroll
  for (int i = 0; i < 4; i++) {
    int j = t + 256 * i;
    float e = powf(10000.f, (2.f * (float)j) * (1.f / 1024.f));
    float arg = tv / e;
    float te = ((j & 1) == 0) ? sinf(arg) : cosf(arg);
    float c = l0 * Wl[j * 2 + 0] + l1 * Wl[j * 2 + 1] + bl[j] + te;
    cs[b * 1024 + j] = seluf(c);
  }
}

// ---------------- row LN + modulate -> bf16 (layer 0 only; zeroes tails)
__global__ __launch_bounds__(256) void k_lnmod(
    const float* __restrict__ x, const float* __restrict__ shiftB, const float* __restrict__ scaleB,
    int bstride, const int* __restrict__ cnt, const int* __restrict__ start,
    const int* __restrict__ t2b, bf16* __restrict__ out)
{
  int row = blockIdx.x, t = threadIdx.x;
  if (row >= start[8]) return;
  int tb = t2b[row >> 6], slot = row - start[tb];
  if (slot >= cnt[tb]) {
    s4v z = {0, 0, 0, 0};
    *(s4v*)&out[(size_t)row * 1024 + t * 4] = z;
    return;
  }
  const float* xr = x + (size_t)row * 1024;
  f4v v = *(const f4v*)&xr[t * 4];
  float s = v[0] + v[1] + v[2] + v[3];
  float ss = v[0]*v[0] + v[1]*v[1] + v[2]*v[2] + v[3]*v[3];
  #pragma unroll
  for (int off = 32; off; off >>= 1) { s += __shfl_xor(s, off); ss += __shfl_xor(ss, off); }
  __shared__ float rs[4], rss[4];
  int w = t >> 6;
  if ((t & 63) == 0) { rs[w] = s; rss[w] = ss; }
  __syncthreads();
  s = rs[0] + rs[1] + rs[2] + rs[3];
  ss = rss[0] + rss[1] + rss[2] + rss[3];
  float mean = s * (1.f / 1024.f);
  float var = ss * (1.f / 1024.f) - mean * mean;
  float rstd = rsqrtf(var + 1e-6f);
  f4v sh = *(const f4v*)&shiftB[(size_t)tb * bstride + t * 4];
  f4v sc = *(const f4v*)&scaleB[(size_t)tb * bstride + t * 4];
  s4v o;
  #pragma unroll
  for (int i = 0; i < 4; i++)
    o[i] = (short)f2bu((v[i] - mean) * rstd * (1.f + sc[i]) + sh[i]);
  *(s4v*)&out[(size_t)row * 1024 + t * 4] = o;
}

// ---------------- x += gm*att; h2 = modulate(ln(x), sf, cf) -> bf16 (tails -> 0)
__global__ __launch_bounds__(256) void k_resid(
    float* __restrict__ x, const bf16* __restrict__ att, const float* __restrict__ m6b,
    const int* __restrict__ cnt, const int* __restrict__ start,
    const int* __restrict__ t2b, bf16* __restrict__ h2)
{
  int row = blockIdx.x, t = threadIdx.x;
  if (row >= start[8]) return;
  int tb = t2b[row >> 6], slot = row - start[tb];
  if (slot >= cnt[tb]) {
    s4v z = {0, 0, 0, 0};
    *(s4v*)&h2[(size_t)row * 1024 + t * 4] = z;
    return;
  }
  float* xr = x + (size_t)row * 1024;
  const float* gm = m6b + (size_t)tb * 6144 + 2048;
  const float* sf = m6b + (size_t)tb * 6144 + 3072;
  const float* cf = m6b + (size_t)tb * 6144 + 4096;
  f4v xv = *(const f4v*)&xr[t * 4];
  s4v av = *(const s4v*)&att[((size_t)tb * 512 + slot) * 1024 + t * 4];
  f4v gv = *(const f4v*)&gm[t * 4];
  f4v vv;
  #pragma unroll
  for (int i = 0; i < 4; i++) vv[i] = xv[i] + gv[i] * bfbits(av[i]);
  *(f4v*)&xr[t * 4] = vv;
  float s = vv[0] + vv[1] + vv[2] + vv[3];
  float ss = vv[0]*vv[0] + vv[1]*vv[1] + vv[2]*vv[2] + vv[3]*vv[3];
  #pragma unroll
  for (int off = 32; off; off >>= 1) { s += __shfl_xor(s, off); ss += __shfl_xor(ss, off); }
  __shared__ float rs[4], rss[4];
  int w = t >> 6;
  if ((t & 63) == 0) { rs[w] = s; rss[w] = ss; }
  __syncthreads();
  s = rs[0] + rs[1] + rs[2] + rs[3];
  ss = rss[0] + rss[1] + rss[2] + rss[3];
  float mean = s * (1.f / 1024.f);
  float var = ss * (1.f / 1024.f) - mean * mean;
  float rstd = rsqrtf(var + 1e-6f);
  f4v sfv = *(const f4v*)&sf[t * 4];
  f4v cfv = *(const f4v*)&cf[t * 4];
  s4v o;
  #pragma unroll
  for (int i = 0; i < 4; i++)
    o[i] = (short)f2bu((vv[i] - mean) * rstd * (1.f + cfv[i]) + sfv[i]);
  *(s4v*)&h2[(size_t)row * 1024 + t * 4] = o;
}

// ---------------- MFMA flash attention + fused next-layer weight conversion.
__global__ __launch_bounds__(256) void k_attn(
    const bf16* __restrict__ q, const bf16* __restrict__ k, const bf16* __restrict__ vt,
    const int* __restrict__ cnt, bf16* __restrict__ att,
    const float* __restrict__ nwq, const float* __restrict__ nwk, const float* __restrict__ nwv,
    const float* __restrict__ nw1, const float* __restrict__ nw2,
    bf16* __restrict__ dqkv, bf16* __restrict__ dw1, bf16* __restrict__ dw2, int mode)
{
  if (blockIdx.x >= 4) {
    int cid = (blockIdx.x - 4) * 128 + blockIdx.y;
    int i0 = cid * 256 + threadIdx.x;
    #pragma unroll
    for (int half = 0; half < 2; half++) {
      int j = i0 * 2 + half;
      if (mode == 1) {
        if (j < 131072) conv8(nwq + (size_t)j * 8, dqkv + (size_t)j * 8);
      } else {
        if (j < 393216) {
          int o = j * 8;
          int row = o >> 10, col = o & 1023;
          int sel = row >> 10, sr = row & 1023;
          conv8((sel == 0 ? nwq : sel == 1 ? nwk : nwv) + (size_t)sr * 1024 + col, dqkv + o);
        } else if (j < 917504) {
          size_t o = (size_t)(j - 393216) * 8;
          conv8(nw1 + o, dw1 + o);
        } else {
          size_t o = (size_t)(j - 917504) * 8;
          conv8(nw2 + o, dw2 + o);
        }
      }
    }
    return;
  }

  int bh = blockIdx.y, b = bh >> 4, hh = bh & 15;
  int cntb = cnt[b];
  if ((int)blockIdx.x * 128 >= cntb) return;
  int t = threadIdx.x, w = t >> 6, lane = t & 63;
  int fr = lane & 15, g = lane >> 4;
  int qw = blockIdx.x * 128 + w * 32;
  const size_t ho = (size_t)bh * (512 * 64);

  __shared__ bf16 Pb[4][32][72];

  s8v qf[2][2];
  #pragma unroll
  for (int mf = 0; mf < 2; mf++)
    #pragma unroll
    for (int kk = 0; kk < 2; kk++)
      qf[mf][kk] = *(const s8v*)(q + ho + (size_t)(qw + mf * 16 + fr) * 64 + kk * 32 + g * 8);

  float mrow[2][4], lsum[2][4];
  f4v oacc[2][4];
  const f4v vzero = {0.f, 0.f, 0.f, 0.f};
  #pragma unroll
  for (int mf = 0; mf < 2; mf++)
    #pragma unroll
    for (int r = 0; r < 4; r++) { mrow[mf][r] = -3.0e38f; lsum[mf][r] = 0.f; }
  #pragma unroll
  for (int mf = 0; mf < 2; mf++)
    #pragma unroll
    for (int nd = 0; nd < 4; nd++) oacc[mf][nd] = vzero;

  int nkt = (cntb + 63) >> 6;
  for (int kt = 0; kt < nkt; kt++) {
    int kb0 = kt * 64;
    f4v sacc[2][4];
    #pragma unroll
    for (int mf = 0; mf < 2; mf++)
      #pragma unroll
      for (int nf = 0; nf < 4; nf++) sacc[mf][nf] = vzero;
    #pragma unroll
    for (int kk = 0; kk < 2; kk++) {
      s8v kf[4];
      #pragma unroll
      for (int nf = 0; nf < 4; nf++)
        kf[nf] = *(const s8v*)(k + ho + (size_t)(kb0 + nf * 16 + fr) * 64 + kk * 32 + g * 8);
      #pragma unroll
      for (int mf = 0; mf < 2; mf++)
        #pragma unroll
        for (int nf = 0; nf < 4; nf++)
          sacc[mf][nf] = __builtin_amdgcn_mfma_f32_16x16x32_bf16(qf[mf][kk], kf[nf], sacc[mf][nf], 0, 0, 0);
    }
    #pragma unroll
    for (int mf = 0; mf < 2; mf++) {
      #pragma unroll
      for (int r = 0; r < 4; r++) {
        float mx = -3.0e38f;
        #pragma unroll
        for (int nf = 0; nf < 4; nf++) {
          float s = sacc[mf][nf][r] * TPINV;
          if (kb0 + nf * 16 + fr >= cntb) s = -1.0e30f;
          sacc[mf][nf][r] = s;
          mx = fmaxf(mx, s);
        }
        mx = fmaxf(mx, __shfl_xor(mx, 1));
        mx = fmaxf(mx, __shfl_xor(mx, 2));
        mx = fmaxf(mx, __shfl_xor(mx, 4));
        mx = fmaxf(mx, __shfl_xor(mx, 8));
        float mnew = fmaxf(mrow[mf][r], mx);
        float corr = __expf(mrow[mf][r] - mnew);
        mrow[mf][r] = mnew;
        float ps = 0.f;
        #pragma unroll
        for (int nf = 0; nf < 4; nf++) {
          float p = __expf(sacc[mf][nf][r] - mnew);
          ps += p;
          Pb[w][mf * 16 + g * 4 + r][nf * 16 + fr] = __float2bfloat16(p);
        }
        lsum[mf][r] = lsum[mf][r] * corr + ps;
        #pragma unroll
        for (int nd = 0; nd < 4; nd++) oacc[mf][nd][r] *= corr;
      }
    }
    #pragma unroll
    for (int kk = 0; kk < 2; kk++) {
      s8v pf[2], vf[4];
      #pragma unroll
      for (int mf = 0; mf < 2; mf++)
        pf[mf] = *(const s8v*)&Pb[w][mf * 16 + fr][kk * 32 + g * 8];
      #pragma unroll
      for (int nd = 0; nd < 4; nd++)
        vf[nd] = *(const s8v*)(vt + ho + (size_t)(nd * 16 + fr) * 512 + kb0 + kk * 32 + g * 8);
      #pragma unroll
      for (int mf = 0; mf < 2; mf++)
        #pragma unroll
        for (int nd = 0; nd < 4; nd++)
          oacc[mf][nd] = __builtin_amdgcn_mfma_f32_16x16x32_bf16(pf[mf], vf[nd], oacc[mf][nd], 0, 0, 0);
    }
  }
  float inv[2][4];
  #pragma unroll
  for (int mf = 0; mf < 2; mf++)
    #pragma unroll
    for (int r = 0; r < 4; r++) {
      float ls = lsum[mf][r];
      ls += __shfl_xor(ls, 1);
      ls += __shfl_xor(ls, 2);
      ls += __shfl_xor(ls, 4);
      ls += __shfl_xor(ls, 8);
      inv[mf][r] = 1.f / ls;
    }
  #pragma unroll
  for (int mf = 0; mf < 2; mf++)
    #pragma unroll
    for (int nd = 0; nd < 4; nd++)
      #pragma unroll
      for (int r = 0; r < 4; r++) {
        int row = qw + mf * 16 + g * 4 + r;
        att[(size_t)(b * 512 + row) * 1024 + hh * 64 + nd * 16 + fr] =
            __float2bfloat16(oacc[mf][nd][r] * inv[mf][r]);
      }
}

// ---------------- GEMM: 32x32x16 MFMA + XOR-swizzled LDS, BM/BN templated.
// Block BM x BN, 4 waves (2x2); wave = (BM/2) x (BN/2), frags of 32.
// EPI: 0=QKV store (Q,K:(b,h,slot,D); V:(b,h,D,slot)), 1=selu+bias->bf16,
//      3=bias->f32, 4=bf16 partial (split-K)
template <int EPI, int BM, int BN>
__global__ __launch_bounds__(256) void k_gemm(
    const bf16* __restrict__ A, const bf16* __restrict__ W,
    const float* __restrict__ bias, int Kst, int kLen, int Ncols,
    const int* __restrict__ cnt, const int* __restrict__ start, const int* __restrict__ t2b,
    bf16* __restrict__ outb, float* __restrict__ outf)
{
  constexpr int MFR = BM / 64;     // m-frags (32 rows) per wave
  constexpr int NFR = BN / 64;     // n-frags (32 cols) per wave
  constexpr int NA  = BM / 32;     // A staging insts per thread
  constexpr int NW  = BN / 32;     // W staging insts per thread
  __shared__ bf16 As[BM][64];
  __shared__ bf16 Ws[BN][64];
  int t = threadIdx.x, lane = t & 63, w = t >> 6;
  int wr = w >> 1, wc = w & 1;
  int m0 = blockIdx.y * BM, n0 = blockIdx.x * BN;
  if (m0 >= start[8]) return;
  int kOff = blockIdx.z * kLen;
  int r32 = lane & 31, hi = lane >> 5;

  const bf16* Abase = A + (size_t)m0 * Kst + kOff;
  const bf16* Wbase = W + (size_t)n0 * Kst + kOff;

  f16v acc[MFR][NFR];
  #pragma unroll
  for (int i = 0; i < MFR; i++)
    #pragma unroll
    for (int j = 0; j < NFR; j++)
      #pragma unroll
      for (int e = 0; e < 16; e++) acc[i][j][e] = 0.f;

  int nkt = kLen >> 6;
  for (int kt = 0; kt < nkt; kt++) {
    int k0 = kt << 6;
    __syncthreads();
    // stage tiles: LDS dest linear, global source pre-swizzled slot^=(row&7)
    #pragma unroll
    for (int i = 0; i < NA; i++) {
      int Z = w * (NA * 1024) + i * 1024 + lane * 16;
      int row = Z >> 7, slot = (Z >> 4) & 7;
      int ss = slot ^ (row & 7);
      gl16(Abase + (size_t)row * Kst + k0 + ss * 8, (char*)As + Z);
    }
    #pragma unroll
    for (int i = 0; i < NW; i++) {
      int Z = w * (NW * 1024) + i * 1024 + lane * 16;
      int row = Z >> 7, slot = (Z >> 4) & 7;
      int ss = slot ^ (row & 7);
      gl16(Wbase + (size_t)row * Kst + k0 + ss * 8, (char*)Ws + Z);
    }
    __syncthreads();
    #pragma unroll
    for (int kk = 0; kk < 4; kk++) {
      s8v af[MFR], bfr[NFR];
      #pragma unroll
      for (int mf = 0; mf < MFR; mf++) {
        int row = wr * (BM / 2) + mf * 32 + r32;
        int sl = (kk * 2 + hi) ^ (row & 7);
        af[mf] = *(const s8v*)((const char*)As + row * 128 + sl * 16);
      }
      #pragma unroll
      for (int nf = 0; nf < NFR; nf++) {
        int row = wc * (BN / 2) + nf * 32 + r32;
        int sl = (kk * 2 + hi) ^ (row & 7);
        bfr[nf] = *(const s8v*)((const char*)Ws + row * 128 + sl * 16);
      }
      #pragma unroll
      for (int mf = 0; mf < MFR; mf++)
        #pragma unroll
        for (int nf = 0; nf < NFR; nf++)
          acc[mf][nf] = __builtin_amdgcn_mfma_f32_32x32x16_bf16(af[mf], bfr[nf], acc[mf][nf], 0, 0, 0);
    }
  }

  // epilogue: C/D layout col=lane&31, row=(reg&3)+8*(reg>>2)+4*hi
  int tb = t2b[m0 >> 6];
  int sb = start[tb];
  #pragma unroll
  for (int mf = 0; mf < MFR; mf++) {
    #pragma unroll
    for (int nf = 0; nf < NFR; nf++) {
      int col = n0 + wc * (BN / 2) + nf * 32 + r32;
      #pragma unroll
      for (int qd = 0; qd < 4; qd++) {
        int row0 = m0 + wr * (BM / 2) + mf * 32 + qd * 8 + hi * 4;
        if (EPI == 0) {
          int sel = col >> 10, cl = col & 1023;
          int nn = row0 - sb;
          int h2 = cl >> 6, dd = cl & 63;
          if (sel == 2) {
            s4v o4;
            #pragma unroll
            for (int r = 0; r < 4; r++) o4[r] = (short)f2bu(acc[mf][nf][qd * 4 + r]);
            *(s4v*)&outb[(size_t)2 * 4194304 + (((size_t)tb * 16 + h2) * 64 + dd) * 512 + nn] = o4;
          } else {
            #pragma unroll
            for (int r = 0; r < 4; r++)
              outb[(size_t)sel * 4194304 + (((size_t)tb * 16 + h2) * 512 + (nn + r)) * 64 + dd] =
                  __float2bfloat16(acc[mf][nf][qd * 4 + r]);
          }
        } else {
          #pragma unroll
          for (int r = 0; r < 4; r++) {
            int row = row0 + r;
            float val = acc[mf][nf][qd * 4 + r];
            if (EPI == 1) {
              outb[(size_t)row * Ncols + col] = __float2bfloat16(seluf(val + bias[col]));
            } else if (EPI == 3) {
              outf[(size_t)row * 1024 + col] = val + bias[col];
            } else {
              outb[(size_t)blockIdx.z * 4194304 + (size_t)row * 1024 + col] = __float2bfloat16(val);
            }
          }
        }
      }
    }
  }
}

// ---------------- split-K(8) combine + residual + NEXT-layer LN/modulate -> h
__global__ __launch_bounds__(256) void k_comb(
    const bf16* __restrict__ part, const float* __restrict__ bias,
    const float* __restrict__ gfb, const float* __restrict__ shiftN,
    const float* __restrict__ scaleN, int strideN,
    float* __restrict__ x, const int* __restrict__ cnt, const int* __restrict__ start,
    const int* __restrict__ t2b, bf16* __restrict__ h)
{
  int row = blockIdx.x, t = threadIdx.x;
  if (row >= start[8]) return;
  int tb = t2b[row >> 6], slot = row - start[tb];
  if (slot >= cnt[tb]) return;  // h tail slots stay zero (written once by layer-0 lnmod)
  size_t o = (size_t)row * 1024 + t * 4;
  f4v sum = {0.f, 0.f, 0.f, 0.f};
  #pragma unroll
  for (int p = 0; p < 8; p++) {
    s4v pv = *(const s4v*)&part[o + (size_t)p * 4194304];
    #pragma unroll
    for (int i = 0; i < 4; i++) sum[i] += bfbits(pv[i]);
  }
  f4v bv = *(const f4v*)&bias[t * 4];
  f4v gf = *(const f4v*)&gfb[(size_t)tb * 6144 + t * 4];
  f4v xv = *(const f4v*)&x[o];
  f4v vv;
  #pragma unroll
  for (int i = 0; i < 4; i++)
    vv[i] = xv[i] + gf[i] * (sum[i] + bv[i]);
  *(f4v*)&x[o] = vv;
  float s = vv[0] + vv[1] + vv[2] + vv[3];
  float ss = vv[0]*vv[0] + vv[1]*vv[1] + vv[2]*vv[2] + vv[3]*vv[3];
  #pragma unroll
  for (int off = 32; off; off >>= 1) { s += __shfl_xor(s, off); ss += __shfl_xor(ss, off); }
  __shared__ float rs[4], rss[4];
  int w = t >> 6;
  if ((t & 63) == 0) { rs[w] = s; rss[w] = ss; }
  __syncthreads();
  s = rs[0] + rs[1] + rs[2] + rs[3];
  ss = rss[0] + rss[1] + rss[2] + rss[3];
  float mean = s * (1.f / 1024.f);
  float var = ss * (1.f / 1024.f) - mean * mean;
  float rstd = rsqrtf(var + 1e-6f);
  f4v sh = *(const f4v*)&shiftN[(size_t)tb * strideN + t * 4];
  f4v sc = *(const f4v*)&scaleN[(size_t)tb * strideN + t * 4];
  s4v ho;
  #pragma unroll
  for (int i = 0; i < 4; i++)
    ho[i] = (short)f2bu((vv[i] - mean) * rstd * (1.f + sc[i]) + sh[i]);
  *(s4v*)&h[(size_t)row * 1024 + t * 4] = ho;
}

extern "C" void kernel_launch(void* const* d_in, const int* in_sizes, int n_in,
                              void* d_out, int out_size, void* d_ws, size_t ws_size,
                              hipStream_t stream)
{
  const float* x_in  = (const float*)d_in[0];
  const float* tim   = (const float*)d_in[1];
  const float* lab   = (const float*)d_in[2];
  const float* xmask = (const float*)d_in[3];
  const float* Wl  = (const float*)d_in[4];
  const float* bl  = (const float*)d_in[5];
  const float* Wq  = (const float*)d_in[6];
  const float* Wk  = (const float*)d_in[7];
  const float* Wv  = (const float*)d_in[8];
  const float* W1  = (const float*)d_in[9];
  const float* b1  = (const float*)d_in[10];
  const float* W2  = (const float*)d_in[11];
  const float* b2  = (const float*)d_in[12];
  const float* Wm  = (const float*)d_in[13];
  const float* bm  = (const float*)d_in[14];
  const float* Wf  = (const float*)d_in[15];
  const float* bfp = (const float*)d_in[16];
  const float* Wmf = (const float*)d_in[17];
  const float* bmf = (const float*)d_in[18];

  char* ws = (char*)d_ws;
  float* x     = (float*)(ws + 0);          // 16777216 B (global compacted)
  float* cs    = (float*)(ws + 16777216);   // 32768 B
  float* mAll  = (float*)(ws + 16809984);   // 1572864 B  [L][B][6144]
  float* m2v   = (float*)(ws + 18382848);   // 65536 B    [B][2048]
  bf16*  h     = (bf16*)(ws + 18448384);    // 8388608 B
  bf16*  qb    = (bf16*)(ws + 26836992);    // 8388608 B  (B,H,slot,D)
  bf16*  kb    = (bf16*)(ws + 35225600);    // 8388608 B  (B,H,slot,D)
  bf16*  vb    = (bf16*)(ws + 43614208);    // 8388608 B  (B,H,D,slot) V^T
  bf16*  att   = (bf16*)(ws + 52002816);    // 8388608 B  (B,slot,C)
  bf16*  f1    = (bf16*)(ws + 60391424);    // 33554432 B (4096 x 4096)
  bf16*  wqkv0 = (bf16*)(ws + 93945856);    // 6291456 B
  bf16*  w1b0  = (bf16*)(ws + 100237312);   // 8388608 B
  bf16*  w2b0  = (bf16*)(ws + 108625920);   // 8388608 B
  bf16*  wfb   = (bf16*)(ws + 117014528);   // 2097152 B
  float* ffin  = (float*)(ws + 119111680);  // 16777216 B
  int*   idxb  = (int*)(ws + 135888896);    // 16384 B
  int*   posb  = (int*)(ws + 135905280);    // 16384 B
  int*   cntb  = (int*)(ws + 135921664);    // 64 B
  int*   strtb = (int*)(ws + 135921728);    // 64 B (start[9])
  int*   t2bb  = (int*)(ws + 135921792);    // 256 B (t2b[64], 64-row gran)
  bf16*  wqkv1 = (bf16*)(ws + 135925760);   // 6291456 B
  bf16*  w1b1  = (bf16*)(ws + 142217216);   // 8388608 B
  bf16*  w2b1  = (bf16*)(ws + 150605824);   // 8388608 B
  bf16*  part  = (bf16*)(ws + 158994432);   // 67108864 B (8 x 4096 x 1024 bf16)

  bf16* wqkvS[2] = { wqkv0, wqkv1 };
  bf16* w1S[2]   = { w1b0, w1b1 };
  bf16* w2S[2]   = { w2b0, w2b1 };

  k_compact<<<1, 512, 0, stream>>>(xmask, idxb, posb, cntb, strtb, t2bb);
  k_cond<<<8, 256, 0, stream>>>(tim, lab, Wl, bl, cs);
  k_prolog<<<22528, 256, 0, stream>>>(x_in, idxb, cntb, strtb, t2bb, x,
                                      Wq, Wk, Wv, W1, W2, wqkv0, w1b0, w2b0,
                                      cs, Wm, bm, mAll, Wmf, bmf, m2v);
  k_lnmod<<<4096, 256, 0, stream>>>(x, mAll + 0, mAll + 1024, 6144, cntb, strtb, t2bb, h);

  for (int l = 0; l < 8; l++) {
    const float* m6b = mAll + (size_t)l * 49152;
    int sel = l & 1, nsel = sel ^ 1;
    int last = (l == 7);

    k_gemm<0, 64, 64><<<dim3(48, 64), 256, 0, stream>>>(h, wqkvS[sel], nullptr, 1024, 1024, 3072,
                                                        cntb, strtb, t2bb, qb, nullptr);
    if (!last) {
      k_attn<<<dim3(26, 128), 256, 0, stream>>>(qb, kb, vb, cntb, att,
          Wq + (size_t)(l + 1) * 1048576, Wk + (size_t)(l + 1) * 1048576,
          Wv + (size_t)(l + 1) * 1048576, W1 + (size_t)(l + 1) * 4194304,
          W2 + (size_t)(l + 1) * 4194304,
          wqkvS[nsel], w1S[nsel], w2S[nsel], 0);
    } else {
      k_attn<<<dim3(26, 128), 256, 0, stream>>>(qb, kb, vb, cntb, att,
          Wf, Wf, Wf, Wf, Wf, wfb, wfb, wfb, 1);
    }
    k_resid<<<4096, 256, 0, stream>>>(x, att, m6b, cntb, strtb, t2bb, h);
    k_gemm<1, 64, 64><<<dim3(64, 64), 256, 0, stream>>>(h, w1S[sel], b1 + l * 4096, 1024, 1024, 4096,
                                                        cntb, strtb, t2bb, f1, nullptr);
    k_gemm<4, 128, 128><<<dim3(8, 32, 8), 256, 0, stream>>>(f1, w2S[sel], nullptr, 4096, 512, 1024,
                                                            cntb, strtb, t2bb, part, nullptr);
    const float* nShift = last ? m2v : (mAll + (size_t)(l + 1) * 49152);
    const float* nScale = last ? (m2v + 1024) : (mAll + (size_t)(l + 1) * 49152 + 1024);
    int nStride = last ? 2048 : 6144;
    k_comb<<<4096, 256, 0, stream>>>(part, b2 + l * 1024, m6b + 5120,
                                     nShift, nScale, nStride,
                                     x, cntb, strtb, t2bb, h);
  }

  k_gemm<3, 64, 64><<<dim3(16, 64), 256, 0, stream>>>(h, wfb, bfp, 1024, 1024, 1024,
                                                      cntb, strtb, t2bb, nullptr, ffin);
  k_scatter<<<4096, 256, 0, stream>>>(ffin, posb, strtb, (float*)d_out);
}

// Round 10
// 1357.221 us; speedup vs baseline: 1.0488x; 1.0488x over previous
//
#include <hip/hip_runtime.h>
#include <hip/hip_bf16.h>
#include <cstddef>

#define DEVI __device__ __forceinline__

typedef __attribute__((ext_vector_type(4))) float f4v;
typedef __attribute__((ext_vector_type(16))) float f16v;
typedef __attribute__((ext_vector_type(8))) short s8v;
typedef __attribute__((ext_vector_type(4))) short s4v;

using bf16 = __hip_bfloat16;

// L=8, B=8, N=512, C=1024, H=16, D=64
constexpr float SELU_A = 1.6732632423543772f;
constexpr float SELU_S = 1.0507009873554805f;
constexpr float TPINV  = 0.08838834764831845f; // 1/sqrt(2*D)

DEVI float bfbits(short s) { return __uint_as_float(((unsigned)(unsigned short)s) << 16); }
DEVI unsigned short f2bu(float f) {
  bf16 h = __float2bfloat16(f);
  return __builtin_bit_cast(unsigned short, h);
}
DEVI float seluf(float x) { return x > 0.f ? SELU_S * x : SELU_S * SELU_A * (__expf(x) - 1.f); }

DEVI void gl16(const void* g, void* l) {
  __builtin_amdgcn_global_load_lds((__attribute__((address_space(1))) void*)g,
                                   (__attribute__((address_space(3))) void*)l, 16, 0, 0);
}

DEVI void conv8(const float* __restrict__ src, bf16* __restrict__ dst) {
  f4v a = *(const f4v*)src;
  f4v b = *(const f4v*)(src + 4);
  s8v o;
  #pragma unroll
  for (int j = 0; j < 4; j++) { o[j] = (short)f2bu(a[j]); o[4 + j] = (short)f2bu(b[j]); }
  *(s8v*)dst = o;
}

// ---------------- mask compaction: global 128-aligned packing; t2b at 64-row granularity
__global__ void k_compact(const float* __restrict__ xm, int* __restrict__ idx,
                          int* __restrict__ pos, int* __restrict__ cnt,
                          int* __restrict__ start, int* __restrict__ t2b)
{
  int t = threadIdx.x;           // 512 threads, wave w = batch w
  int b = t >> 6, lane = t & 63;
  __shared__ int scnt[8];
  int base = b * 512 + lane * 8;
  int mb[8]; int lc = 0;
  #pragma unroll
  for (int i = 0; i < 8; i++) { mb[i] = (xm[base + i] != 0.f) ? 1 : 0; lc += mb[i]; }
  int s = lc;
  #pragma unroll
  for (int o = 1; o < 64; o <<= 1) { int tt = __shfl_up(s, o); if (lane >= o) s += tt; }
  int run = s - lc;
  #pragma unroll
  for (int i = 0; i < 8; i++) {
    int n = lane * 8 + i;
    if (mb[i]) { idx[b * 512 + run] = n; pos[b * 512 + n] = run; run++; }
    else pos[b * 512 + n] = -1;
  }
  if (lane == 63) scnt[b] = s;
  __syncthreads();
  if (t == 0) {
    int st = 0, tile = 0;
    for (int bb = 0; bb < 8; bb++) {
      cnt[bb] = scnt[bb];
      start[bb] = st;
      int nt = (scnt[bb] + 127) >> 7;
      for (int k = 0; k < nt * 2; k++) t2b[tile++] = bb;  // 64-row granularity
      st += nt * 128;
    }
    start[8] = st;
    for (; tile < 64; tile++) t2b[tile] = 0;
  }
}

// ---------------- fused prologue: gather | layer-0 weight conv | m6/m2 matvec (vectorized)
__global__ __launch_bounds__(256) void k_prolog(
    const float* __restrict__ xin, const int* __restrict__ idx, const int* __restrict__ cnt,
    const int* __restrict__ start, const int* __restrict__ t2b, float* __restrict__ xc,
    const float* __restrict__ wq, const float* __restrict__ wk, const float* __restrict__ wv,
    const float* __restrict__ w1, const float* __restrict__ w2,
    bf16* __restrict__ wqkvb, bf16* __restrict__ w1b, bf16* __restrict__ w2b,
    const float* __restrict__ cs, const float* __restrict__ Wm, const float* __restrict__ bm,
    float* __restrict__ mAll, const float* __restrict__ Wmf, const float* __restrict__ bmf,
    float* __restrict__ m2v)
{
  int bid = blockIdx.x, t = threadIdx.x;
  __shared__ float cls[8192];
  if (bid < 4096) {
    int row = bid;
    if (row >= start[8]) return;
    int tb = t2b[row >> 6], slot = row - start[tb];
    f4v v = {0.f, 0.f, 0.f, 0.f};
    if (slot < cnt[tb])
      v = *(const f4v*)&xin[((size_t)tb * 512 + idx[tb * 512 + slot]) * 1024 + t * 4];
    *(f4v*)&xc[(size_t)row * 1024 + t * 4] = v;
  } else if (bid < 9728) {
    int i = (bid - 4096) * 256 + t;
    if (i < 393216) {
      int o = i * 8;
      int row = o >> 10, col = o & 1023;
      int sel = row >> 10, sr = row & 1023;
      conv8((sel == 0 ? wq : sel == 1 ? wk : wv) + (size_t)sr * 1024 + col, wqkvb + o);
    } else if (i < 917504) {
      size_t o = (size_t)(i - 393216) * 8;
      conv8(w1 + o, w1b + o);
    } else {
      size_t o = (size_t)(i - 917504) * 8;
      conv8(w2 + o, w2b + o);
    }
  } else {
    int mode = (bid < 22016) ? 0 : 1;
    const float* W = mode ? Wmf : Wm;
    const float* bias = mode ? bmf : bm;
    float* out = mode ? m2v : mAll;
    int O = mode ? 2048 : 49152;
    int ob = mode ? (bid - 22016) : (bid - 9728);
    #pragma unroll
    for (int i = 0; i < 8; i++)
      *(f4v*)&cls[i * 1024 + t * 4] = *(const f4v*)&cs[i * 1024 + t * 4];
    __syncthreads();
    int w = t >> 6, l = t & 63;
    int o = ob * 4 + w;
    if (o >= O) return;
    const float* Wr = W + (size_t)o * 1024;
    f4v wv[4];
    #pragma unroll
    for (int i = 0; i < 4; i++) wv[i] = *(const f4v*)&Wr[i * 256 + l * 4];
    float acc[8] = {0.f, 0.f, 0.f, 0.f, 0.f, 0.f, 0.f, 0.f};
    #pragma unroll
    for (int i = 0; i < 4; i++) {
      #pragma unroll
      for (int b = 0; b < 8; b++) {
        f4v cv = *(const f4v*)&cls[b * 1024 + i * 256 + l * 4];
        acc[b] += wv[i][0] * cv[0] + wv[i][1] * cv[1] + wv[i][2] * cv[2] + wv[i][3] * cv[3];
      }
    }
    #pragma unroll
    for (int b = 0; b < 8; b++) {
      #pragma unroll
      for (int off = 32; off; off >>= 1) acc[b] += __shfl_xor(acc[b], off);
    }
    float bv = bias[o];
    #pragma unroll
    for (int b = 0; b < 8; b++) {
      if (l == b) {
        float val = acc[b] + bv;
        size_t dst;
        if (mode == 0) { int ll = o / 6144, ft = o - ll * 6144; dst = ((size_t)ll * 8 + b) * 6144 + ft; }
        else dst = (size_t)b * 2048 + o;
        out[dst] = val;
      }
    }
  }
}

// ---------------- scatter final rows back; dead rows = 0
__global__ __launch_bounds__(256) void k_scatter(const float* __restrict__ ffin,
    const int* __restrict__ pos, const int* __restrict__ start, float* __restrict__ out)
{
  int row = blockIdx.x, t = threadIdx.x, b = row >> 9;
  int p = pos[row];
  f4v v = {0.f, 0.f, 0.f, 0.f};
  if (p >= 0) v = *(const f4v*)&ffin[(size_t)(start[b] + p) * 1024 + t * 4];
  *(f4v*)&out[(size_t)row * 1024 + t * 4] = v;
}

// ---------------- conditioning
__global__ void k_cond(const float* __restrict__ tim, const float* __restrict__ lab,
                       const float* __restrict__ Wl, const float* __restrict__ bl,
                       float* __restrict__ cs)
{
  int b = blockIdx.x, t = threadIdx.x;
  float l0 = lab[b * 2 + 0], l1 = lab[b * 2 + 1], tv = tim[b];
  #pragma unroll
  for (int i = 0; i < 4; i++) {
    int j = t + 256 * i;
    float e = powf(10000.f, (2.f * (float)j) * (1.f / 1024.f));
    float arg = tv / e;
    float te = ((j & 1) == 0) ? sinf(arg) : cosf(arg);
    float c = l0 * Wl[j * 2 + 0] + l1 * Wl[j * 2 + 1] + bl[j] + te;
    cs[b * 1024 + j] = seluf(c);
  }
}

// ---------------- row LN + modulate -> bf16 (layer 0 only; zeroes tails)
__global__ __launch_bounds__(256) void k_lnmod(
    const float* __restrict__ x, const float* __restrict__ shiftB, const float* __restrict__ scaleB,
    int bstride, const int* __restrict__ cnt, const int* __restrict__ start,
    const int* __restrict__ t2b, bf16* __restrict__ out)
{
  int row = blockIdx.x, t = threadIdx.x;
  if (row >= start[8]) return;
  int tb = t2b[row >> 6], slot = row - start[tb];
  if (slot >= cnt[tb]) {
    s4v z = {0, 0, 0, 0};
    *(s4v*)&out[(size_t)row * 1024 + t * 4] = z;
    return;
  }
  const float* xr = x + (size_t)row * 1024;
  f4v v = *(const f4v*)&xr[t * 4];
  float s = v[0] + v[1] + v[2] + v[3];
  float ss = v[0]*v[0] + v[1]*v[1] + v[2]*v[2] + v[3]*v[3];
  #pragma unroll
  for (int off = 32; off; off >>= 1) { s += __shfl_xor(s, off); ss += __shfl_xor(ss, off); }
  __shared__ float rs[4], rss[4];
  int w = t >> 6;
  if ((t & 63) == 0) { rs[w] = s; rss[w] = ss; }
  __syncthreads();
  s = rs[0] + rs[1] + rs[2] + rs[3];
  ss = rss[0] + rss[1] + rss[2] + rss[3];
  float mean = s * (1.f / 1024.f);
  float var = ss * (1.f / 1024.f) - mean * mean;
  float rstd = rsqrtf(var + 1e-6f);
  f4v sh = *(const f4v*)&shiftB[(size_t)tb * bstride + t * 4];
  f4v sc = *(const f4v*)&scaleB[(size_t)tb * bstride + t * 4];
  s4v o;
  #pragma unroll
  for (int i = 0; i < 4; i++)
    o[i] = (short)f2bu((v[i] - mean) * rstd * (1.f + sc[i]) + sh[i]);
  *(s4v*)&out[(size_t)row * 1024 + t * 4] = o;
}

// ---------------- x += gm*att; h2 = modulate(ln(x), sf, cf) -> bf16 (tails -> 0)
__global__ __launch_bounds__(256) void k_resid(
    float* __restrict__ x, const bf16* __restrict__ att, const float* __restrict__ m6b,
    const int* __restrict__ cnt, const int* __restrict__ start,
    const int* __restrict__ t2b, bf16* __restrict__ h2)
{
  int row = blockIdx.x, t = threadIdx.x;
  if (row >= start[8]) return;
  int tb = t2b[row >> 6], slot = row - start[tb];
  if (slot >= cnt[tb]) {
    s4v z = {0, 0, 0, 0};
    *(s4v*)&h2[(size_t)row * 1024 + t * 4] = z;
    return;
  }
  float* xr = x + (size_t)row * 1024;
  const float* gm = m6b + (size_t)tb * 6144 + 2048;
  const float* sf = m6b + (size_t)tb * 6144 + 3072;
  const float* cf = m6b + (size_t)tb * 6144 + 4096;
  f4v xv = *(const f4v*)&xr[t * 4];
  s4v av = *(const s4v*)&att[((size_t)tb * 512 + slot) * 1024 + t * 4];
  f4v gv = *(const f4v*)&gm[t * 4];
  f4v vv;
  #pragma unroll
  for (int i = 0; i < 4; i++) vv[i] = xv[i] + gv[i] * bfbits(av[i]);
  *(f4v*)&xr[t * 4] = vv;
  float s = vv[0] + vv[1] + vv[2] + vv[3];
  float ss = vv[0]*vv[0] + vv[1]*vv[1] + vv[2]*vv[2] + vv[3]*vv[3];
  #pragma unroll
  for (int off = 32; off; off >>= 1) { s += __shfl_xor(s, off); ss += __shfl_xor(ss, off); }
  __shared__ float rs[4], rss[4];
  int w = t >> 6;
  if ((t & 63) == 0) { rs[w] = s; rss[w] = ss; }
  __syncthreads();
  s = rs[0] + rs[1] + rs[2] + rs[3];
  ss = rss[0] + rss[1] + rss[2] + rss[3];
  float mean = s * (1.f / 1024.f);
  float var = ss * (1.f / 1024.f) - mean * mean;
  float rstd = rsqrtf(var + 1e-6f);
  f4v sfv = *(const f4v*)&sf[t * 4];
  f4v cfv = *(const f4v*)&cf[t * 4];
  s4v o;
  #pragma unroll
  for (int i = 0; i < 4; i++)
    o[i] = (short)f2bu((vv[i] - mean) * rstd * (1.f + cfv[i]) + sfv[i]);
  *(s4v*)&h2[(size_t)row * 1024 + t * 4] = o;
}

// ---------------- MFMA flash attention + fused next-layer weight conversion.
__global__ __launch_bounds__(256) void k_attn(
    const bf16* __restrict__ q, const bf16* __restrict__ k, const bf16* __restrict__ vt,
    const int* __restrict__ cnt, bf16* __restrict__ att,
    const float* __restrict__ nwq, const float* __restrict__ nwk, const float* __restrict__ nwv,
    const float* __restrict__ nw1, const float* __restrict__ nw2,
    bf16* __restrict__ dqkv, bf16* __restrict__ dw1, bf16* __restrict__ dw2, int mode)
{
  if (blockIdx.x >= 4) {
    int cid = (blockIdx.x - 4) * 128 + blockIdx.y;
    int i0 = cid * 256 + threadIdx.x;
    #pragma unroll
    for (int half = 0; half < 2; half++) {
      int j = i0 * 2 + half;
      if (mode == 1) {
        if (j < 131072) conv8(nwq + (size_t)j * 8, dqkv + (size_t)j * 8);
      } else {
        if (j < 393216) {
          int o = j * 8;
          int row = o >> 10, col = o & 1023;
          int sel = row >> 10, sr = row & 1023;
          conv8((sel == 0 ? nwq : sel == 1 ? nwk : nwv) + (size_t)sr * 1024 + col, dqkv + o);
        } else if (j < 917504) {
          size_t o = (size_t)(j - 393216) * 8;
          conv8(nw1 + o, dw1 + o);
        } else {
          size_t o = (size_t)(j - 917504) * 8;
          conv8(nw2 + o, dw2 + o);
        }
      }
    }
    return;
  }

  int bh = blockIdx.y, b = bh >> 4, hh = bh & 15;
  int cntb = cnt[b];
  if ((int)blockIdx.x * 128 >= cntb) return;
  int t = threadIdx.x, w = t >> 6, lane = t & 63;
  int fr = lane & 15, g = lane >> 4;
  int qw = blockIdx.x * 128 + w * 32;
  const size_t ho = (size_t)bh * (512 * 64);

  __shared__ bf16 Pb[4][32][72];

  s8v qf[2][2];
  #pragma unroll
  for (int mf = 0; mf < 2; mf++)
    #pragma unroll
    for (int kk = 0; kk < 2; kk++)
      qf[mf][kk] = *(const s8v*)(q + ho + (size_t)(qw + mf * 16 + fr) * 64 + kk * 32 + g * 8);

  float mrow[2][4], lsum[2][4];
  f4v oacc[2][4];
  const f4v vzero = {0.f, 0.f, 0.f, 0.f};
  #pragma unroll
  for (int mf = 0; mf < 2; mf++)
    #pragma unroll
    for (int r = 0; r < 4; r++) { mrow[mf][r] = -3.0e38f; lsum[mf][r] = 0.f; }
  #pragma unroll
  for (int mf = 0; mf < 2; mf++)
    #pragma unroll
    for (int nd = 0; nd < 4; nd++) oacc[mf][nd] = vzero;

  int nkt = (cntb + 63) >> 6;
  for (int kt = 0; kt < nkt; kt++) {
    int kb0 = kt * 64;
    f4v sacc[2][4];
    #pragma unroll
    for (int mf = 0; mf < 2; mf++)
      #pragma unroll
      for (int nf = 0; nf < 4; nf++) sacc[mf][nf] = vzero;
    #pragma unroll
    for (int kk = 0; kk < 2; kk++) {
      s8v kf[4];
      #pragma unroll
      for (int nf = 0; nf < 4; nf++)
        kf[nf] = *(const s8v*)(k + ho + (size_t)(kb0 + nf * 16 + fr) * 64 + kk * 32 + g * 8);
      #pragma unroll
      for (int mf = 0; mf < 2; mf++)
        #pragma unroll
        for (int nf = 0; nf < 4; nf++)
          sacc[mf][nf] = __builtin_amdgcn_mfma_f32_16x16x32_bf16(qf[mf][kk], kf[nf], sacc[mf][nf], 0, 0, 0);
    }
    #pragma unroll
    for (int mf = 0; mf < 2; mf++) {
      #pragma unroll
      for (int r = 0; r < 4; r++) {
        float mx = -3.0e38f;
        #pragma unroll
        for (int nf = 0; nf < 4; nf++) {
          float s = sacc[mf][nf][r] * TPINV;
          if (kb0 + nf * 16 + fr >= cntb) s = -1.0e30f;
          sacc[mf][nf][r] = s;
          mx = fmaxf(mx, s);
        }
        mx = fmaxf(mx, __shfl_xor(mx, 1));
        mx = fmaxf(mx, __shfl_xor(mx, 2));
        mx = fmaxf(mx, __shfl_xor(mx, 4));
        mx = fmaxf(mx, __shfl_xor(mx, 8));
        float mnew = fmaxf(mrow[mf][r], mx);
        float corr = __expf(mrow[mf][r] - mnew);
        mrow[mf][r] = mnew;
        float ps = 0.f;
        #pragma unroll
        for (int nf = 0; nf < 4; nf++) {
          float p = __expf(sacc[mf][nf][r] - mnew);
          ps += p;
          Pb[w][mf * 16 + g * 4 + r][nf * 16 + fr] = __float2bfloat16(p);
        }
        lsum[mf][r] = lsum[mf][r] * corr + ps;
        #pragma unroll
        for (int nd = 0; nd < 4; nd++) oacc[mf][nd][r] *= corr;
      }
    }
    #pragma unroll
    for (int kk = 0; kk < 2; kk++) {
      s8v pf[2], vf[4];
      #pragma unroll
      for (int mf = 0; mf < 2; mf++)
        pf[mf] = *(const s8v*)&Pb[w][mf * 16 + fr][kk * 32 + g * 8];
      #pragma unroll
      for (int nd = 0; nd < 4; nd++)
        vf[nd] = *(const s8v*)(vt + ho + (size_t)(nd * 16 + fr) * 512 + kb0 + kk * 32 + g * 8);
      #pragma unroll
      for (int mf = 0; mf < 2; mf++)
        #pragma unroll
        for (int nd = 0; nd < 4; nd++)
          oacc[mf][nd] = __builtin_amdgcn_mfma_f32_16x16x32_bf16(pf[mf], vf[nd], oacc[mf][nd], 0, 0, 0);
    }
  }
  float inv[2][4];
  #pragma unroll
  for (int mf = 0; mf < 2; mf++)
    #pragma unroll
    for (int r = 0; r < 4; r++) {
      float ls = lsum[mf][r];
      ls += __shfl_xor(ls, 1);
      ls += __shfl_xor(ls, 2);
      ls += __shfl_xor(ls, 4);
      ls += __shfl_xor(ls, 8);
      inv[mf][r] = 1.f / ls;
    }
  #pragma unroll
  for (int mf = 0; mf < 2; mf++)
    #pragma unroll
    for (int nd = 0; nd < 4; nd++)
      #pragma unroll
      for (int r = 0; r < 4; r++) {
        int row = qw + mf * 16 + g * 4 + r;
        att[(size_t)(b * 512 + row) * 1024 + hh * 64 + nd * 16 + fr] =
            __float2bfloat16(oacc[mf][nd][r] * inv[mf][r]);
      }
}

// ---------------- GEMM: 32x32x16 MFMA + XOR-swizzled LDS, BM/BN templated.
// Block BM x BN, 4 waves (2x2); wave = (BM/2) x (BN/2), frags of 32.
// EPI: 0=QKV store (Q,K:(b,h,slot,D); V:(b,h,D,slot)), 1=selu+bias->bf16,
//      3=bias->f32, 4=bf16 partial (split-K)
template <int EPI, int BM, int BN>
__global__ __launch_bounds__(256) void k_gemm(
    const bf16* __restrict__ A, const bf16* __restrict__ W,
    const float* __restrict__ bias, int Kst, int kLen, int Ncols,
    const int* __restrict__ cnt, const int* __restrict__ start, const int* __restrict__ t2b,
    bf16* __restrict__ outb, float* __restrict__ outf)
{
  constexpr int MFR = BM / 64;     // m-frags (32 rows) per wave
  constexpr int NFR = BN / 64;     // n-frags (32 cols) per wave
  constexpr int NA  = BM / 32;     // A staging insts per thread
  constexpr int NW  = BN / 32;     // W staging insts per thread
  __shared__ bf16 As[BM][64];
  __shared__ bf16 Ws[BN][64];
  int t = threadIdx.x, lane = t & 63, w = t >> 6;
  int wr = w >> 1, wc = w & 1;
  int m0 = blockIdx.y * BM, n0 = blockIdx.x * BN;
  if (m0 >= start[8]) return;
  int kOff = blockIdx.z * kLen;
  int r32 = lane & 31, hi = lane >> 5;

  const bf16* Abase = A + (size_t)m0 * Kst + kOff;
  const bf16* Wbase = W + (size_t)n0 * Kst + kOff;

  f16v acc[MFR][NFR];
  #pragma unroll
  for (int i = 0; i < MFR; i++)
    #pragma unroll
    for (int j = 0; j < NFR; j++)
      #pragma unroll
      for (int e = 0; e < 16; e++) acc[i][j][e] = 0.f;

  int nkt = kLen >> 6;
  for (int kt = 0; kt < nkt; kt++) {
    int k0 = kt << 6;
    __syncthreads();
    // stage tiles: LDS dest linear, global source pre-swizzled slot^=(row&7)
    #pragma unroll
    for (int i = 0; i < NA; i++) {
      int Z = w * (NA * 1024) + i * 1024 + lane * 16;
      int row = Z >> 7, slot = (Z >> 4) & 7;
      int ss = slot ^ (row & 7);
      gl16(Abase + (size_t)row * Kst + k0 + ss * 8, (char*)As + Z);
    }
    #pragma unroll
    for (int i = 0; i < NW; i++) {
      int Z = w * (NW * 1024) + i * 1024 + lane * 16;
      int row = Z >> 7, slot = (Z >> 4) & 7;
      int ss = slot ^ (row & 7);
      gl16(Wbase + (size_t)row * Kst + k0 + ss * 8, (char*)Ws + Z);
    }
    __syncthreads();
    #pragma unroll
    for (int kk = 0; kk < 4; kk++) {
      s8v af[MFR], bfr[NFR];
      #pragma unroll
      for (int mf = 0; mf < MFR; mf++) {
        int row = wr * (BM / 2) + mf * 32 + r32;
        int sl = (kk * 2 + hi) ^ (row & 7);
        af[mf] = *(const s8v*)((const char*)As + row * 128 + sl * 16);
      }
      #pragma unroll
      for (int nf = 0; nf < NFR; nf++) {
        int row = wc * (BN / 2) + nf * 32 + r32;
        int sl = (kk * 2 + hi) ^ (row & 7);
        bfr[nf] = *(const s8v*)((const char*)Ws + row * 128 + sl * 16);
      }
      #pragma unroll
      for (int mf = 0; mf < MFR; mf++)
        #pragma unroll
        for (int nf = 0; nf < NFR; nf++)
          acc[mf][nf] = __builtin_amdgcn_mfma_f32_32x32x16_bf16(af[mf], bfr[nf], acc[mf][nf], 0, 0, 0);
    }
  }

  // epilogue: C/D layout col=lane&31, row=(reg&3)+8*(reg>>2)+4*hi
  int tb = t2b[m0 >> 6];
  int sb = start[tb];
  #pragma unroll
  for (int mf = 0; mf < MFR; mf++) {
    #pragma unroll
    for (int nf = 0; nf < NFR; nf++) {
      int col = n0 + wc * (BN / 2) + nf * 32 + r32;
      #pragma unroll
      for (int qd = 0; qd < 4; qd++) {
        int row0 = m0 + wr * (BM / 2) + mf * 32 + qd * 8 + hi * 4;
        if (EPI == 0) {
          int sel = col >> 10, cl = col & 1023;
          int nn = row0 - sb;
          int h2 = cl >> 6, dd = cl & 63;
          if (sel == 2) {
            s4v o4;
            #pragma unroll
            for (int r = 0; r < 4; r++) o4[r] = (short)f2bu(acc[mf][nf][qd * 4 + r]);
            *(s4v*)&outb[(size_t)2 * 4194304 + (((size_t)tb * 16 + h2) * 64 + dd) * 512 + nn] = o4;
          } else {
            #pragma unroll
            for (int r = 0; r < 4; r++)
              outb[(size_t)sel * 4194304 + (((size_t)tb * 16 + h2) * 512 + (nn + r)) * 64 + dd] =
                  __float2bfloat16(acc[mf][nf][qd * 4 + r]);
          }
        } else {
          #pragma unroll
          for (int r = 0; r < 4; r++) {
            int row = row0 + r;
            float val = acc[mf][nf][qd * 4 + r];
            if (EPI == 1) {
              outb[(size_t)row * Ncols + col] = __float2bfloat16(seluf(val + bias[col]));
            } else if (EPI == 3) {
              outf[(size_t)row * 1024 + col] = val + bias[col];
            } else {
              outb[(size_t)blockIdx.z * 4194304 + (size_t)row * 1024 + col] = __float2bfloat16(val);
            }
          }
        }
      }
    }
  }
}

// ---------------- split-K(8) combine + residual + NEXT-layer LN/modulate -> h
__global__ __launch_bounds__(256) void k_comb(
    const bf16* __restrict__ part, const float* __restrict__ bias,
    const float* __restrict__ gfb, const float* __restrict__ shiftN,
    const float* __restrict__ scaleN, int strideN,
    float* __restrict__ x, const int* __restrict__ cnt, const int* __restrict__ start,
    const int* __restrict__ t2b, bf16* __restrict__ h)
{
  int row = blockIdx.x, t = threadIdx.x;
  if (row >= start[8]) return;
  int tb = t2b[row >> 6], slot = row - start[tb];
  if (slot >= cnt[tb]) return;  // h tail slots stay zero (written once by layer-0 lnmod)
  size_t o = (size_t)row * 1024 + t * 4;
  f4v sum = {0.f, 0.f, 0.f, 0.f};
  #pragma unroll
  for (int p = 0; p < 8; p++) {
    s4v pv = *(const s4v*)&part[o + (size_t)p * 4194304];
    #pragma unroll
    for (int i = 0; i < 4; i++) sum[i] += bfbits(pv[i]);
  }
  f4v bv = *(const f4v*)&bias[t * 4];
  f4v gf = *(const f4v*)&gfb[(size_t)tb * 6144 + t * 4];
  f4v xv = *(const f4v*)&x[o];
  f4v vv;
  #pragma unroll
  for (int i = 0; i < 4; i++)
    vv[i] = xv[i] + gf[i] * (sum[i] + bv[i]);
  *(f4v*)&x[o] = vv;
  float s = vv[0] + vv[1] + vv[2] + vv[3];
  float ss = vv[0]*vv[0] + vv[1]*vv[1] + vv[2]*vv[2] + vv[3]*vv[3];
  #pragma unroll
  for (int off = 32; off; off >>= 1) { s += __shfl_xor(s, off); ss += __shfl_xor(ss, off); }
  __shared__ float rs[4], rss[4];
  int w = t >> 6;
  if ((t & 63) == 0) { rs[w] = s; rss[w] = ss; }
  __syncthreads();
  s = rs[0] + rs[1] + rs[2] + rs[3];
  ss = rss[0] + rss[1] + rss[2] + rss[3];
  float mean = s * (1.f / 1024.f);
  float var = ss * (1.f / 1024.f) - mean * mean;
  float rstd = rsqrtf(var + 1e-6f);
  f4v sh = *(const f4v*)&shiftN[(size_t)tb * strideN + t * 4];
  f4v sc = *(const f4v*)&scaleN[(size_t)tb * strideN + t * 4];
  s4v ho;
  #pragma unroll
  for (int i = 0; i < 4; i++)
    ho[i] = (short)f2bu((vv[i] - mean) * rstd * (1.f + sc[i]) + sh[i]);
  *(s4v*)&h[(size_t)row * 1024 + t * 4] = ho;
}

extern "C" void kernel_launch(void* const* d_in, const int* in_sizes, int n_in,
                              void* d_out, int out_size, void* d_ws, size_t ws_size,
                              hipStream_t stream)
{
  const float* x_in  = (const float*)d_in[0];
  const float* tim   = (const float*)d_in[1];
  const float* lab   = (const float*)d_in[2];
  const float* xmask = (const float*)d_in[3];
  const float* Wl  = (const float*)d_in[4];
  const float* bl  = (const float*)d_in[5];
  const float* Wq  = (const float*)d_in[6];
  const float* Wk  = (const float*)d_in[7];
  const float* Wv  = (const float*)d_in[8];
  const float* W1  = (const float*)d_in[9];
  const float* b1  = (const float*)d_in[10];
  const float* W2  = (const float*)d_in[11];
  const float* b2  = (const float*)d_in[12];
  const float* Wm  = (const float*)d_in[13];
  const float* bm  = (const float*)d_in[14];
  const float* Wf  = (const float*)d_in[15];
  const float* bfp = (const float*)d_in[16];
  const float* Wmf = (const float*)d_in[17];
  const float* bmf = (const float*)d_in[18];

  char* ws = (char*)d_ws;
  float* x     = (float*)(ws + 0);          // 16777216 B (global compacted)
  float* cs    = (float*)(ws + 16777216);   // 32768 B
  float* mAll  = (float*)(ws + 16809984);   // 1572864 B  [L][B][6144]
  float* m2v   = (float*)(ws + 18382848);   // 65536 B    [B][2048]
  bf16*  h     = (bf16*)(ws + 18448384);    // 8388608 B
  bf16*  qb    = (bf16*)(ws + 26836992);    // 8388608 B  (B,H,slot,D)
  bf16*  kb    = (bf16*)(ws + 35225600);    // 8388608 B  (B,H,slot,D)
  bf16*  vb    = (bf16*)(ws + 43614208);    // 8388608 B  (B,H,D,slot) V^T
  bf16*  att   = (bf16*)(ws + 52002816);    // 8388608 B  (B,slot,C)
  bf16*  f1    = (bf16*)(ws + 60391424);    // 33554432 B (4096 x 4096)
  bf16*  wqkv0 = (bf16*)(ws + 93945856);    // 6291456 B
  bf16*  w1b0  = (bf16*)(ws + 100237312);   // 8388608 B
  bf16*  w2b0  = (bf16*)(ws + 108625920);   // 8388608 B
  bf16*  wfb   = (bf16*)(ws + 117014528);   // 2097152 B
  float* ffin  = (float*)(ws + 119111680);  // 16777216 B
  int*   idxb  = (int*)(ws + 135888896);    // 16384 B
  int*   posb  = (int*)(ws + 135905280);    // 16384 B
  int*   cntb  = (int*)(ws + 135921664);    // 64 B
  int*   strtb = (int*)(ws + 135921728);    // 64 B (start[9])
  int*   t2bb  = (int*)(ws + 135921792);    // 256 B (t2b[64], 64-row gran)
  bf16*  wqkv1 = (bf16*)(ws + 135925760);   // 6291456 B
  bf16*  w1b1  = (bf16*)(ws + 142217216);   // 8388608 B
  bf16*  w2b1  = (bf16*)(ws + 150605824);   // 8388608 B
  bf16*  part  = (bf16*)(ws + 158994432);   // 67108864 B (8 x 4096 x 1024 bf16)

  bf16* wqkvS[2] = { wqkv0, wqkv1 };
  bf16* w1S[2]   = { w1b0, w1b1 };
  bf16* w2S[2]   = { w2b0, w2b1 };

  k_compact<<<1, 512, 0, stream>>>(xmask, idxb, posb, cntb, strtb, t2bb);
  k_cond<<<8, 256, 0, stream>>>(tim, lab, Wl, bl, cs);
  k_prolog<<<22528, 256, 0, stream>>>(x_in, idxb, cntb, strtb, t2bb, x,
                                      Wq, Wk, Wv, W1, W2, wqkv0, w1b0, w2b0,
                                      cs, Wm, bm, mAll, Wmf, bmf, m2v);
  k_lnmod<<<4096, 256, 0, stream>>>(x, mAll + 0, mAll + 1024, 6144, cntb, strtb, t2bb, h);

  for (int l = 0; l < 8; l++) {
    const float* m6b = mAll + (size_t)l * 49152;
    int sel = l & 1, nsel = sel ^ 1;
    int last = (l == 7);

    k_gemm<0, 128, 64><<<dim3(48, 32), 256, 0, stream>>>(h, wqkvS[sel], nullptr, 1024, 1024, 3072,
                                                         cntb, strtb, t2bb, qb, nullptr);
    if (!last) {
      k_attn<<<dim3(26, 128), 256, 0, stream>>>(qb, kb, vb, cntb, att,
          Wq + (size_t)(l + 1) * 1048576, Wk + (size_t)(l + 1) * 1048576,
          Wv + (size_t)(l + 1) * 1048576, W1 + (size_t)(l + 1) * 4194304,
          W2 + (size_t)(l + 1) * 4194304,
          wqkvS[nsel], w1S[nsel], w2S[nsel], 0);
    } else {
      k_attn<<<dim3(26, 128), 256, 0, stream>>>(qb, kb, vb, cntb, att,
          Wf, Wf, Wf, Wf, Wf, wfb, wfb, wfb, 1);
    }
    k_resid<<<4096, 256, 0, stream>>>(x, att, m6b, cntb, strtb, t2bb, h);
    k_gemm<1, 128, 64><<<dim3(64, 32), 256, 0, stream>>>(h, w1S[sel], b1 + l * 4096, 1024, 1024, 4096,
                                                         cntb, strtb, t2bb, f1, nullptr);
    k_gemm<4, 128, 128><<<dim3(8, 32, 8), 256, 0, stream>>>(f1, w2S[sel], nullptr, 4096, 512, 1024,
                                                            cntb, strtb, t2bb, part, nullptr);
    const float* nShift = last ? m2v : (mAll + (size_t)(l + 1) * 49152);
    const float* nScale = last ? (m2v + 1024) : (mAll + (size_t)(l + 1) * 49152 + 1024);
    int nStride = last ? 2048 : 6144;
    k_comb<<<4096, 256, 0, stream>>>(part, b2 + l * 1024, m6b + 5120,
                                     nShift, nScale, nStride,
                                     x, cntb, strtb, t2bb, h);
  }

  k_gemm<3, 128, 64><<<dim3(16, 32), 256, 0, stream>>>(h, wfb, bfp, 1024, 1024, 1024,
                                                       cntb, strtb, t2bb, nullptr, ffin);
  k_scatter<<<4096, 256, 0, stream>>>(ffin, posb, strtb, (float*)d_out);
}

// Round 11
// 1318.877 us; speedup vs baseline: 1.0793x; 1.0291x over previous
//
#include <hip/hip_runtime.h>
#include <hip/hip_bf16.h>
#include <cstddef>

#define DEVI __device__ __forceinline__

typedef __attribute__((ext_vector_type(4))) float f4v;
typedef __attribute__((ext_vector_type(16))) float f16v;
typedef __attribute__((ext_vector_type(8))) short s8v;
typedef __attribute__((ext_vector_type(4))) short s4v;

using bf16 = __hip_bfloat16;

// L=8, B=8, N=512, C=1024, H=16, D=64
constexpr float SELU_A = 1.6732632423543772f;
constexpr float SELU_S = 1.0507009873554805f;
constexpr float TPINV  = 0.08838834764831845f; // 1/sqrt(2*D)

DEVI float bfbits(short s) { return __uint_as_float(((unsigned)(unsigned short)s) << 16); }
DEVI unsigned short f2bu(float f) {
  bf16 h = __float2bfloat16(f);
  return __builtin_bit_cast(unsigned short, h);
}
DEVI float seluf(float x) { return x > 0.f ? SELU_S * x : SELU_S * SELU_A * (__expf(x) - 1.f); }

DEVI void gl16(const void* g, void* l) {
  __builtin_amdgcn_global_load_lds((__attribute__((address_space(1))) void*)g,
                                   (__attribute__((address_space(3))) void*)l, 16, 0, 0);
}

DEVI void conv8(const float* __restrict__ src, bf16* __restrict__ dst) {
  f4v a = *(const f4v*)src;
  f4v b = *(const f4v*)(src + 4);
  s8v o;
  #pragma unroll
  for (int j = 0; j < 4; j++) { o[j] = (short)f2bu(a[j]); o[4 + j] = (short)f2bu(b[j]); }
  *(s8v*)dst = o;
}

// matvec: 16 outputs per 256-thread block (4 per wave), all W loads pre-issued.
// out[b*stride + o] = sum_k cls[b][k]*W[o][k] + bias[o], b in [0,8)
DEVI void matvec16(const float* __restrict__ W, const float* __restrict__ bias,
                   float* __restrict__ out, const float* cls, int base, int O, int stride)
{
  int t = threadIdx.x, w = t >> 6, l = t & 63;
  int o0 = base + w * 4;
  if (o0 >= O) return;
  f4v wv[4][4];
  #pragma unroll
  for (int r = 0; r < 4; r++)
    #pragma unroll
    for (int i = 0; i < 4; i++)
      wv[r][i] = *(const f4v*)&W[(size_t)(o0 + r) * 1024 + i * 256 + l * 4];
  #pragma unroll
  for (int r = 0; r < 4; r++) {
    float acc[8] = {0.f, 0.f, 0.f, 0.f, 0.f, 0.f, 0.f, 0.f};
    #pragma unroll
    for (int i = 0; i < 4; i++) {
      #pragma unroll
      for (int b = 0; b < 8; b++) {
        f4v cv = *(const f4v*)&cls[b * 1024 + i * 256 + l * 4];
        acc[b] += wv[r][i][0] * cv[0] + wv[r][i][1] * cv[1] +
                  wv[r][i][2] * cv[2] + wv[r][i][3] * cv[3];
      }
    }
    #pragma unroll
    for (int b = 0; b < 8; b++) {
      #pragma unroll
      for (int off = 32; off; off >>= 1) acc[b] += __shfl_xor(acc[b], off);
    }
    float bv = bias[o0 + r];
    #pragma unroll
    for (int b = 0; b < 8; b++)
      if (l == b) out[(size_t)b * stride + o0 + r] = acc[b] + bv;
  }
}

// ---------------- mask compaction: global 128-aligned packing; t2b at 64-row granularity
__global__ void k_compact(const float* __restrict__ xm, int* __restrict__ idx,
                          int* __restrict__ pos, int* __restrict__ cnt,
                          int* __restrict__ start, int* __restrict__ t2b)
{
  int t = threadIdx.x;           // 512 threads, wave w = batch w
  int b = t >> 6, lane = t & 63;
  __shared__ int scnt[8];
  int base = b * 512 + lane * 8;
  int mb[8]; int lc = 0;
  #pragma unroll
  for (int i = 0; i < 8; i++) { mb[i] = (xm[base + i] != 0.f) ? 1 : 0; lc += mb[i]; }
  int s = lc;
  #pragma unroll
  for (int o = 1; o < 64; o <<= 1) { int tt = __shfl_up(s, o); if (lane >= o) s += tt; }
  int run = s - lc;
  #pragma unroll
  for (int i = 0; i < 8; i++) {
    int n = lane * 8 + i;
    if (mb[i]) { idx[b * 512 + run] = n; pos[b * 512 + n] = run; run++; }
    else pos[b * 512 + n] = -1;
  }
  if (lane == 63) scnt[b] = s;
  __syncthreads();
  if (t == 0) {
    int st = 0, tile = 0;
    for (int bb = 0; bb < 8; bb++) {
      cnt[bb] = scnt[bb];
      start[bb] = st;
      int nt = (scnt[bb] + 127) >> 7;
      for (int k = 0; k < nt * 2; k++) t2b[tile++] = bb;  // 64-row granularity
      st += nt * 128;
    }
    start[8] = st;
    for (; tile < 64; tile++) t2b[tile] = 0;
  }
}

// ---------------- fused prologue: gather | layer-0 weight conv | layer-0 m6 + m2 matvec
__global__ __launch_bounds__(256) void k_prolog(
    const float* __restrict__ xin, const int* __restrict__ idx, const int* __restrict__ cnt,
    const int* __restrict__ start, const int* __restrict__ t2b, float* __restrict__ xc,
    const float* __restrict__ wq, const float* __restrict__ wk, const float* __restrict__ wv,
    const float* __restrict__ w1, const float* __restrict__ w2,
    bf16* __restrict__ wqkvb, bf16* __restrict__ w1b, bf16* __restrict__ w2b,
    const float* __restrict__ cs, const float* __restrict__ Wm, const float* __restrict__ bm,
    float* __restrict__ mAll, const float* __restrict__ Wmf, const float* __restrict__ bmf,
    float* __restrict__ m2v)
{
  int bid = blockIdx.x, t = threadIdx.x;
  __shared__ float cls[8192];
  if (bid < 4096) {
    int row = bid;
    if (row >= start[8]) return;
    int tb = t2b[row >> 6], slot = row - start[tb];
    f4v v = {0.f, 0.f, 0.f, 0.f};
    if (slot < cnt[tb])
      v = *(const f4v*)&xin[((size_t)tb * 512 + idx[tb * 512 + slot]) * 1024 + t * 4];
    *(f4v*)&xc[(size_t)row * 1024 + t * 4] = v;
  } else if (bid < 9728) {
    int i = (bid - 4096) * 256 + t;
    if (i < 393216) {
      int o = i * 8;
      int row = o >> 10, col = o & 1023;
      int sel = row >> 10, sr = row & 1023;
      conv8((sel == 0 ? wq : sel == 1 ? wk : wv) + (size_t)sr * 1024 + col, wqkvb + o);
    } else if (i < 917504) {
      size_t o = (size_t)(i - 393216) * 8;
      conv8(w1 + o, w1b + o);
    } else {
      size_t o = (size_t)(i - 917504) * 8;
      conv8(w2 + o, w2b + o);
    }
  } else {
    #pragma unroll
    for (int i = 0; i < 8; i++)
      *(f4v*)&cls[i * 1024 + t * 4] = *(const f4v*)&cs[i * 1024 + t * 4];
    __syncthreads();
    if (bid < 10112)
      matvec16(Wm, bm, mAll, cls, (bid - 9728) * 16, 6144, 6144);      // layer-0 m6
    else
      matvec16(Wmf, bmf, m2v, cls, (bid - 10112) * 16, 2048, 2048);    // m2
  }
}

// ---------------- scatter final rows back; dead rows = 0
__global__ __launch_bounds__(256) void k_scatter(const float* __restrict__ ffin,
    const int* __restrict__ pos, const int* __restrict__ start, float* __restrict__ out)
{
  int row = blockIdx.x, t = threadIdx.x, b = row >> 9;
  int p = pos[row];
  f4v v = {0.f, 0.f, 0.f, 0.f};
  if (p >= 0) v = *(const f4v*)&ffin[(size_t)(start[b] + p) * 1024 + t * 4];
  *(f4v*)&out[(size_t)row * 1024 + t * 4] = v;
}

// ---------------- conditioning
__global__ void k_cond(const float* __restrict__ tim, const float* __restrict__ lab,
                       const float* __restrict__ Wl, const float* __restrict__ bl,
                       float* __restrict__ cs)
{
  int b = blockIdx.x, t = threadIdx.x;
  float l0 = lab[b * 2 + 0], l1 = lab[b * 2 + 1], tv = tim[b];
  #pragma unroll
  for (int i = 0; i < 4; i++) {
    int j = t + 256 * i;
    float e = powf(10000.f, (2.f * (float)j) * (1.f / 1024.f));
    float arg = tv / e;
    float te = ((j & 1) == 0) ? sinf(arg) : cosf(arg);
    float c = l0 * Wl[j * 2 + 0] + l1 * Wl[j * 2 + 1] + bl[j] + te;
    cs[b * 1024 + j] = seluf(c);
  }
}

// ---------------- row LN + modulate -> bf16 (layer 0 only; zeroes tails)
__global__ __launch_bounds__(256) void k_lnmod(
    const float* __restrict__ x, const float* __restrict__ shiftB, const float* __restrict__ scaleB,
    int bstride, const int* __restrict__ cnt, const int* __restrict__ start,
    const int* __restrict__ t2b, bf16* __restrict__ out)
{
  int row = blockIdx.x, t = threadIdx.x;
  if (row >= start[8]) return;
  int tb = t2b[row >> 6], slot = row - start[tb];
  if (slot >= cnt[tb]) {
    s4v z = {0, 0, 0, 0};
    *(s4v*)&out[(size_t)row * 1024 + t * 4] = z;
    return;
  }
  const float* xr = x + (size_t)row * 1024;
  f4v v = *(const f4v*)&xr[t * 4];
  float s = v[0] + v[1] + v[2] + v[3];
  float ss = v[0]*v[0] + v[1]*v[1] + v[2]*v[2] + v[3]*v[3];
  #pragma unroll
  for (int off = 32; off; off >>= 1) { s += __shfl_xor(s, off); ss += __shfl_xor(ss, off); }
  __shared__ float rs[4], rss[4];
  int w = t >> 6;
  if ((t & 63) == 0) { rs[w] = s; rss[w] = ss; }
  __syncthreads();
  s = rs[0] + rs[1] + rs[2] + rs[3];
  ss = rss[0] + rss[1] + rss[2] + rss[3];
  float mean = s * (1.f / 1024.f);
  float var = ss * (1.f / 1024.f) - mean * mean;
  float rstd = rsqrtf(var + 1e-6f);
  f4v sh = *(const f4v*)&shiftB[(size_t)tb * bstride + t * 4];
  f4v sc = *(const f4v*)&scaleB[(size_t)tb * bstride + t * 4];
  s4v o;
  #pragma unroll
  for (int i = 0; i < 4; i++)
    o[i] = (short)f2bu((v[i] - mean) * rstd * (1.f + sc[i]) + sh[i]);
  *(s4v*)&out[(size_t)row * 1024 + t * 4] = o;
}

// ---------------- x += gm*att; h2 = modulate(ln(x), sf, cf) -> bf16 (tails -> 0)
__global__ __launch_bounds__(256) void k_resid(
    float* __restrict__ x, const bf16* __restrict__ att, const float* __restrict__ m6b,
    const int* __restrict__ cnt, const int* __restrict__ start,
    const int* __restrict__ t2b, bf16* __restrict__ h2)
{
  int row = blockIdx.x, t = threadIdx.x;
  if (row >= start[8]) return;
  int tb = t2b[row >> 6], slot = row - start[tb];
  if (slot >= cnt[tb]) {
    s4v z = {0, 0, 0, 0};
    *(s4v*)&h2[(size_t)row * 1024 + t * 4] = z;
    return;
  }
  float* xr = x + (size_t)row * 1024;
  const float* gm = m6b + (size_t)tb * 6144 + 2048;
  const float* sf = m6b + (size_t)tb * 6144 + 3072;
  const float* cf = m6b + (size_t)tb * 6144 + 4096;
  f4v xv = *(const f4v*)&xr[t * 4];
  s4v av = *(const s4v*)&att[((size_t)tb * 512 + slot) * 1024 + t * 4];
  f4v gv = *(const f4v*)&gm[t * 4];
  f4v vv;
  #pragma unroll
  for (int i = 0; i < 4; i++) vv[i] = xv[i] + gv[i] * bfbits(av[i]);
  *(f4v*)&xr[t * 4] = vv;
  float s = vv[0] + vv[1] + vv[2] + vv[3];
  float ss = vv[0]*vv[0] + vv[1]*vv[1] + vv[2]*vv[2] + vv[3]*vv[3];
  #pragma unroll
  for (int off = 32; off; off >>= 1) { s += __shfl_xor(s, off); ss += __shfl_xor(ss, off); }
  __shared__ float rs[4], rss[4];
  int w = t >> 6;
  if ((t & 63) == 0) { rs[w] = s; rss[w] = ss; }
  __syncthreads();
  s = rs[0] + rs[1] + rs[2] + rs[3];
  ss = rss[0] + rss[1] + rss[2] + rss[3];
  float mean = s * (1.f / 1024.f);
  float var = ss * (1.f / 1024.f) - mean * mean;
  float rstd = rsqrtf(var + 1e-6f);
  f4v sfv = *(const f4v*)&sf[t * 4];
  f4v cfv = *(const f4v*)&cf[t * 4];
  s4v o;
  #pragma unroll
  for (int i = 0; i < 4; i++)
    o[i] = (short)f2bu((vv[i] - mean) * rstd * (1.f + cfv[i]) + sfv[i]);
  *(s4v*)&h2[(size_t)row * 1024 + t * 4] = o;
}

// ---------------- MFMA flash attention + fused next-layer weight conversion + next-layer m6.
// blockIdx.x < 4: attention; [4,26): weight conv; [26,29): m6[l+1] matvec (mode 0 only).
__global__ __launch_bounds__(256) void k_attn(
    const bf16* __restrict__ q, const bf16* __restrict__ k, const bf16* __restrict__ vt,
    const int* __restrict__ cnt, bf16* __restrict__ att,
    const float* __restrict__ nwq, const float* __restrict__ nwk, const float* __restrict__ nwv,
    const float* __restrict__ nw1, const float* __restrict__ nw2,
    bf16* __restrict__ dqkv, bf16* __restrict__ dw1, bf16* __restrict__ dw2, int mode,
    const float* __restrict__ cs, const float* __restrict__ WmN,
    const float* __restrict__ bmN, float* __restrict__ m6out)
{
  __shared__ __attribute__((aligned(16))) char smem[32768];
  if (blockIdx.x >= 26) {
    if (mode == 1) return;
    float* cls = (float*)smem;
    int t = threadIdx.x;
    #pragma unroll
    for (int i = 0; i < 8; i++)
      *(f4v*)&cls[i * 1024 + t * 4] = *(const f4v*)&cs[i * 1024 + t * 4];
    __syncthreads();
    int mid = (blockIdx.x - 26) * 128 + blockIdx.y;
    matvec16(WmN, bmN, m6out, cls, mid * 16, 6144, 6144);
    return;
  }
  if (blockIdx.x >= 4) {
    int cid = (blockIdx.x - 4) * 128 + blockIdx.y;
    int i0 = cid * 256 + threadIdx.x;
    #pragma unroll
    for (int half = 0; half < 2; half++) {
      int j = i0 * 2 + half;
      if (mode == 1) {
        if (j < 131072) conv8(nwq + (size_t)j * 8, dqkv + (size_t)j * 8);
      } else {
        if (j < 393216) {
          int o = j * 8;
          int row = o >> 10, col = o & 1023;
          int sel = row >> 10, sr = row & 1023;
          conv8((sel == 0 ? nwq : sel == 1 ? nwk : nwv) + (size_t)sr * 1024 + col, dqkv + o);
        } else if (j < 917504) {
          size_t o = (size_t)(j - 393216) * 8;
          conv8(nw1 + o, dw1 + o);
        } else {
          size_t o = (size_t)(j - 917504) * 8;
          conv8(nw2 + o, dw2 + o);
        }
      }
    }
    return;
  }

  int bh = blockIdx.y, b = bh >> 4, hh = bh & 15;
  int cntb = cnt[b];
  if ((int)blockIdx.x * 128 >= cntb) return;
  int t = threadIdx.x, w = t >> 6, lane = t & 63;
  int fr = lane & 15, g = lane >> 4;
  int qw = blockIdx.x * 128 + w * 32;
  const size_t ho = (size_t)bh * (512 * 64);

  typedef bf16 PbRow[32][72];
  PbRow* Pb = (PbRow*)smem;

  s8v qf[2][2];
  #pragma unroll
  for (int mf = 0; mf < 2; mf++)
    #pragma unroll
    for (int kk = 0; kk < 2; kk++)
      qf[mf][kk] = *(const s8v*)(q + ho + (size_t)(qw + mf * 16 + fr) * 64 + kk * 32 + g * 8);

  float mrow[2][4], lsum[2][4];
  f4v oacc[2][4];
  const f4v vzero = {0.f, 0.f, 0.f, 0.f};
  #pragma unroll
  for (int mf = 0; mf < 2; mf++)
    #pragma unroll
    for (int r = 0; r < 4; r++) { mrow[mf][r] = -3.0e38f; lsum[mf][r] = 0.f; }
  #pragma unroll
  for (int mf = 0; mf < 2; mf++)
    #pragma unroll
    for (int nd = 0; nd < 4; nd++) oacc[mf][nd] = vzero;

  int nkt = (cntb + 63) >> 6;
  for (int kt = 0; kt < nkt; kt++) {
    int kb0 = kt * 64;
    f4v sacc[2][4];
    #pragma unroll
    for (int mf = 0; mf < 2; mf++)
      #pragma unroll
      for (int nf = 0; nf < 4; nf++) sacc[mf][nf] = vzero;
    #pragma unroll
    for (int kk = 0; kk < 2; kk++) {
      s8v kf[4];
      #pragma unroll
      for (int nf = 0; nf < 4; nf++)
        kf[nf] = *(const s8v*)(k + ho + (size_t)(kb0 + nf * 16 + fr) * 64 + kk * 32 + g * 8);
      #pragma unroll
      for (int mf = 0; mf < 2; mf++)
        #pragma unroll
        for (int nf = 0; nf < 4; nf++)
          sacc[mf][nf] = __builtin_amdgcn_mfma_f32_16x16x32_bf16(qf[mf][kk], kf[nf], sacc[mf][nf], 0, 0, 0);
    }
    #pragma unroll
    for (int mf = 0; mf < 2; mf++) {
      #pragma unroll
      for (int r = 0; r < 4; r++) {
        float mx = -3.0e38f;
        #pragma unroll
        for (int nf = 0; nf < 4; nf++) {
          float s = sacc[mf][nf][r] * TPINV;
          if (kb0 + nf * 16 + fr >= cntb) s = -1.0e30f;
          sacc[mf][nf][r] = s;
          mx = fmaxf(mx, s);
        }
        mx = fmaxf(mx, __shfl_xor(mx, 1));
        mx = fmaxf(mx, __shfl_xor(mx, 2));
        mx = fmaxf(mx, __shfl_xor(mx, 4));
        mx = fmaxf(mx, __shfl_xor(mx, 8));
        float mnew = fmaxf(mrow[mf][r], mx);
        float corr = __expf(mrow[mf][r] - mnew);
        mrow[mf][r] = mnew;
        float ps = 0.f;
        #pragma unroll
        for (int nf = 0; nf < 4; nf++) {
          float p = __expf(sacc[mf][nf][r] - mnew);
          ps += p;
          Pb[w][mf * 16 + g * 4 + r][nf * 16 + fr] = __float2bfloat16(p);
        }
        lsum[mf][r] = lsum[mf][r] * corr + ps;
        #pragma unroll
        for (int nd = 0; nd < 4; nd++) oacc[mf][nd][r] *= corr;
      }
    }
    #pragma unroll
    for (int kk = 0; kk < 2; kk++) {
      s8v pf[2], vf[4];
      #pragma unroll
      for (int mf = 0; mf < 2; mf++)
        pf[mf] = *(const s8v*)&Pb[w][mf * 16 + fr][kk * 32 + g * 8];
      #pragma unroll
      for (int nd = 0; nd < 4; nd++)
        vf[nd] = *(const s8v*)(vt + ho + (size_t)(nd * 16 + fr) * 512 + kb0 + kk * 32 + g * 8);
      #pragma unroll
      for (int mf = 0; mf < 2; mf++)
        #pragma unroll
        for (int nd = 0; nd < 4; nd++)
          oacc[mf][nd] = __builtin_amdgcn_mfma_f32_16x16x32_bf16(pf[mf], vf[nd], oacc[mf][nd], 0, 0, 0);
    }
  }
  float inv[2][4];
  #pragma unroll
  for (int mf = 0; mf < 2; mf++)
    #pragma unroll
    for (int r = 0; r < 4; r++) {
      float ls = lsum[mf][r];
      ls += __shfl_xor(ls, 1);
      ls += __shfl_xor(ls, 2);
      ls += __shfl_xor(ls, 4);
      ls += __shfl_xor(ls, 8);
      inv[mf][r] = 1.f / ls;
    }
  #pragma unroll
  for (int mf = 0; mf < 2; mf++)
    #pragma unroll
    for (int nd = 0; nd < 4; nd++)
      #pragma unroll
      for (int r = 0; r < 4; r++) {
        int row = qw + mf * 16 + g * 4 + r;
        att[(size_t)(b * 512 + row) * 1024 + hh * 64 + nd * 16 + fr] =
            __float2bfloat16(oacc[mf][nd][r] * inv[mf][r]);
      }
}

// ---------------- GEMM: 32x32x16 MFMA + XOR-swizzled LDS, BM/BN templated.
// Block BM x BN, 4 waves (2x2); wave = (BM/2) x (BN/2), frags of 32.
// EPI: 0=QKV store (Q,K:(b,h,slot,D); V:(b,h,D,slot)), 1=selu+bias->bf16,
//      3=bias->f32, 4=bf16 partial (split-K)
template <int EPI, int BM, int BN>
__global__ __launch_bounds__(256) void k_gemm(
    const bf16* __restrict__ A, const bf16* __restrict__ W,
    const float* __restrict__ bias, int Kst, int kLen, int Ncols,
    const int* __restrict__ cnt, const int* __restrict__ start, const int* __restrict__ t2b,
    bf16* __restrict__ outb, float* __restrict__ outf)
{
  constexpr int MFR = BM / 64;     // m-frags (32 rows) per wave
  constexpr int NFR = BN / 64;     // n-frags (32 cols) per wave
  constexpr int NA  = BM / 32;     // A staging insts per thread
  constexpr int NW  = BN / 32;     // W staging insts per thread
  __shared__ bf16 As[BM][64];
  __shared__ bf16 Ws[BN][64];
  int t = threadIdx.x, lane = t & 63, w = t >> 6;
  int wr = w >> 1, wc = w & 1;
  int m0 = blockIdx.y * BM, n0 = blockIdx.x * BN;
  if (m0 >= start[8]) return;
  int kOff = blockIdx.z * kLen;
  int r32 = lane & 31, hi = lane >> 5;

  const bf16* Abase = A + (size_t)m0 * Kst + kOff;
  const bf16* Wbase = W + (size_t)n0 * Kst + kOff;

  f16v acc[MFR][NFR];
  #pragma unroll
  for (int i = 0; i < MFR; i++)
    #pragma unroll
    for (int j = 0; j < NFR; j++)
      #pragma unroll
      for (int e = 0; e < 16; e++) acc[i][j][e] = 0.f;

  int nkt = kLen >> 6;
  for (int kt = 0; kt < nkt; kt++) {
    int k0 = kt << 6;
    __syncthreads();
    // stage tiles: LDS dest linear, global source pre-swizzled slot^=(row&7)
    #pragma unroll
    for (int i = 0; i < NA; i++) {
      int Z = w * (NA * 1024) + i * 1024 + lane * 16;
      int row = Z >> 7, slot = (Z >> 4) & 7;
      int ss = slot ^ (row & 7);
      gl16(Abase + (size_t)row * Kst + k0 + ss * 8, (char*)As + Z);
    }
    #pragma unroll
    for (int i = 0; i < NW; i++) {
      int Z = w * (NW * 1024) + i * 1024 + lane * 16;
      int row = Z >> 7, slot = (Z >> 4) & 7;
      int ss = slot ^ (row & 7);
      gl16(Wbase + (size_t)row * Kst + k0 + ss * 8, (char*)Ws + Z);
    }
    __syncthreads();
    #pragma unroll
    for (int kk = 0; kk < 4; kk++) {
      s8v af[MFR], bfr[NFR];
      #pragma unroll
      for (int mf = 0; mf < MFR; mf++) {
        int row = wr * (BM / 2) + mf * 32 + r32;
        int sl = (kk * 2 + hi) ^ (row & 7);
        af[mf] = *(const s8v*)((const char*)As + row * 128 + sl * 16);
      }
      #pragma unroll
      for (int nf = 0; nf < NFR; nf++) {
        int row = wc * (BN / 2) + nf * 32 + r32;
        int sl = (kk * 2 + hi) ^ (row & 7);
        bfr[nf] = *(const s8v*)((const char*)Ws + row * 128 + sl * 16);
      }
      #pragma unroll
      for (int mf = 0; mf < MFR; mf++)
        #pragma unroll
        for (int nf = 0; nf < NFR; nf++)
          acc[mf][nf] = __builtin_amdgcn_mfma_f32_32x32x16_bf16(af[mf], bfr[nf], acc[mf][nf], 0, 0, 0);
    }
  }

  // epilogue: C/D layout col=lane&31, row=(reg&3)+8*(reg>>2)+4*hi
  int tb = t2b[m0 >> 6];
  int sb = start[tb];
  #pragma unroll
  for (int mf = 0; mf < MFR; mf++) {
    #pragma unroll
    for (int nf = 0; nf < NFR; nf++) {
      int col = n0 + wc * (BN / 2) + nf * 32 + r32;
      #pragma unroll
      for (int qd = 0; qd < 4; qd++) {
        int row0 = m0 + wr * (BM / 2) + mf * 32 + qd * 8 + hi * 4;
        if (EPI == 0) {
          int sel = col >> 10, cl = col & 1023;
          int nn = row0 - sb;
          int h2 = cl >> 6, dd = cl & 63;
          if (sel == 2) {
            s4v o4;
            #pragma unroll
            for (int r = 0; r < 4; r++) o4[r] = (short)f2bu(acc[mf][nf][qd * 4 + r]);
            *(s4v*)&outb[(size_t)2 * 4194304 + (((size_t)tb * 16 + h2) * 64 + dd) * 512 + nn] = o4;
          } else {
            #pragma unroll
            for (int r = 0; r < 4; r++)
              outb[(size_t)sel * 4194304 + (((size_t)tb * 16 + h2) * 512 + (nn + r)) * 64 + dd] =
                  __float2bfloat16(acc[mf][nf][qd * 4 + r]);
          }
        } else {
          #pragma unroll
          for (int r = 0; r < 4; r++) {
            int row = row0 + r;
            float val = acc[mf][nf][qd * 4 + r];
            if (EPI == 1) {
              outb[(size_t)row * Ncols + col] = __float2bfloat16(seluf(val + bias[col]));
            } else if (EPI == 3) {
              outf[(size_t)row * 1024 + col] = val + bias[col];
            } else {
              outb[(size_t)blockIdx.z * 4194304 + (size_t)row * 1024 + col] = __float2bfloat16(val);
            }
          }
        }
      }
    }
  }
}

// ---------------- split-K(8) combine + residual + NEXT-layer LN/modulate -> h
__global__ __launch_bounds__(256) void k_comb(
    const bf16* __restrict__ part, const float* __restrict__ bias,
    const float* __restrict__ gfb, const float* __restrict__ shiftN,
    const float* __restrict__ scaleN, int strideN,
    float* __restrict__ x, const int* __restrict__ cnt, const int* __restrict__ start,
    const int* __restrict__ t2b, bf16* __restrict__ h)
{
  int row = blockIdx.x, t = threadIdx.x;
  if (row >= start[8]) return;
  int tb = t2b[row >> 6], slot = row - start[tb];
  if (slot >= cnt[tb]) return;  // h tail slots stay zero (written once by layer-0 lnmod)
  size_t o = (size_t)row * 1024 + t * 4;
  f4v sum = {0.f, 0.f, 0.f, 0.f};
  #pragma unroll
  for (int p = 0; p < 8; p++) {
    s4v pv = *(const s4v*)&part[o + (size_t)p * 4194304];
    #pragma unroll
    for (int i = 0; i < 4; i++) sum[i] += bfbits(pv[i]);
  }
  f4v bv = *(const f4v*)&bias[t * 4];
  f4v gf = *(const f4v*)&gfb[(size_t)tb * 6144 + t * 4];
  f4v xv = *(const f4v*)&x[o];
  f4v vv;
  #pragma unroll
  for (int i = 0; i < 4; i++)
    vv[i] = xv[i] + gf[i] * (sum[i] + bv[i]);
  *(f4v*)&x[o] = vv;
  float s = vv[0] + vv[1] + vv[2] + vv[3];
  float ss = vv[0]*vv[0] + vv[1]*vv[1] + vv[2]*vv[2] + vv[3]*vv[3];
  #pragma unroll
  for (int off = 32; off; off >>= 1) { s += __shfl_xor(s, off); ss += __shfl_xor(ss, off); }
  __shared__ float rs[4], rss[4];
  int w = t >> 6;
  if ((t & 63) == 0) { rs[w] = s; rss[w] = ss; }
  __syncthreads();
  s = rs[0] + rs[1] + rs[2] + rs[3];
  ss = rss[0] + rss[1] + rss[2] + rss[3];
  float mean = s * (1.f / 1024.f);
  float var = ss * (1.f / 1024.f) - mean * mean;
  float rstd = rsqrtf(var + 1e-6f);
  f4v sh = *(const f4v*)&shiftN[(size_t)tb * strideN + t * 4];
  f4v sc = *(const f4v*)&scaleN[(size_t)tb * strideN + t * 4];
  s4v ho;
  #pragma unroll
  for (int i = 0; i < 4; i++)
    ho[i] = (short)f2bu((vv[i] - mean) * rstd * (1.f + sc[i]) + sh[i]);
  *(s4v*)&h[(size_t)row * 1024 + t * 4] = ho;
}

extern "C" void kernel_launch(void* const* d_in, const int* in_sizes, int n_in,
                              void* d_out, int out_size, void* d_ws, size_t ws_size,
                              hipStream_t stream)
{
  const float* x_in  = (const float*)d_in[0];
  const float* tim   = (const float*)d_in[1];
  const float* lab   = (const float*)d_in[2];
  const float* xmask = (const float*)d_in[3];
  const float* Wl  = (const float*)d_in[4];
  const float* bl  = (const float*)d_in[5];
  const float* Wq  = (const float*)d_in[6];
  const float* Wk  = (const float*)d_in[7];
  const float* Wv  = (const float*)d_in[8];
  const float* W1  = (const float*)d_in[9];
  const float* b1  = (const float*)d_in[10];
  const float* W2  = (const float*)d_in[11];
  const float* b2  = (const float*)d_in[12];
  const float* Wm  = (const float*)d_in[13];
  const float* bm  = (const float*)d_in[14];
  const float* Wf  = (const float*)d_in[15];
  const float* bfp = (const float*)d_in[16];
  const float* Wmf = (const float*)d_in[17];
  const float* bmf = (const float*)d_in[18];

  char* ws = (char*)d_ws;
  float* x     = (float*)(ws + 0);          // 16777216 B (global compacted)
  float* cs    = (float*)(ws + 16777216);   // 32768 B
  float* mAll  = (float*)(ws + 16809984);   // 1572864 B  [L][B][6144]
  float* m2v   = (float*)(ws + 18382848);   // 65536 B    [B][2048]
  bf16*  h     = (bf16*)(ws + 18448384);    // 8388608 B
  bf16*  qb    = (bf16*)(ws + 26836992);    // 8388608 B  (B,H,slot,D)
  bf16*  kb    = (bf16*)(ws + 35225600);    // 8388608 B  (B,H,slot,D)
  bf16*  vb    = (bf16*)(ws + 43614208);    // 8388608 B  (B,H,D,slot) V^T
  bf16*  att   = (bf16*)(ws + 52002816);    // 8388608 B  (B,slot,C)
  bf16*  f1    = (bf16*)(ws + 60391424);    // 33554432 B (4096 x 4096)
  bf16*  wqkv0 = (bf16*)(ws + 93945856);    // 6291456 B
  bf16*  w1b0  = (bf16*)(ws + 100237312);   // 8388608 B
  bf16*  w2b0  = (bf16*)(ws + 108625920);   // 8388608 B
  bf16*  wfb   = (bf16*)(ws + 117014528);   // 2097152 B
  float* ffin  = (float*)(ws + 119111680);  // 16777216 B
  int*   idxb  = (int*)(ws + 135888896);    // 16384 B
  int*   posb  = (int*)(ws + 135905280);    // 16384 B
  int*   cntb  = (int*)(ws + 135921664);    // 64 B
  int*   strtb = (int*)(ws + 135921728);    // 64 B (start[9])
  int*   t2bb  = (int*)(ws + 135921792);    // 256 B (t2b[64], 64-row gran)
  bf16*  wqkv1 = (bf16*)(ws + 135925760);   // 6291456 B
  bf16*  w1b1  = (bf16*)(ws + 142217216);   // 8388608 B
  bf16*  w2b1  = (bf16*)(ws + 150605824);   // 8388608 B
  bf16*  part  = (bf16*)(ws + 158994432);   // 67108864 B (8 x 4096 x 1024 bf16)

  bf16* wqkvS[2] = { wqkv0, wqkv1 };
  bf16* w1S[2]   = { w1b0, w1b1 };
  bf16* w2S[2]   = { w2b0, w2b1 };

  k_compact<<<1, 512, 0, stream>>>(xmask, idxb, posb, cntb, strtb, t2bb);
  k_cond<<<8, 256, 0, stream>>>(tim, lab, Wl, bl, cs);
  k_prolog<<<10240, 256, 0, stream>>>(x_in, idxb, cntb, strtb, t2bb, x,
                                      Wq, Wk, Wv, W1, W2, wqkv0, w1b0, w2b0,
                                      cs, Wm, bm, mAll, Wmf, bmf, m2v);
  k_lnmod<<<4096, 256, 0, stream>>>(x, mAll + 0, mAll + 1024, 6144, cntb, strtb, t2bb, h);

  for (int l = 0; l < 8; l++) {
    const float* m6b = mAll + (size_t)l * 49152;
    int sel = l & 1, nsel = sel ^ 1;
    int last = (l == 7);

    k_gemm<0, 128, 64><<<dim3(48, 32), 256, 0, stream>>>(h, wqkvS[sel], nullptr, 1024, 1024, 3072,
                                                         cntb, strtb, t2bb, qb, nullptr);
    if (!last) {
      k_attn<<<dim3(29, 128), 256, 0, stream>>>(qb, kb, vb, cntb, att,
          Wq + (size_t)(l + 1) * 1048576, Wk + (size_t)(l + 1) * 1048576,
          Wv + (size_t)(l + 1) * 1048576, W1 + (size_t)(l + 1) * 4194304,
          W2 + (size_t)(l + 1) * 4194304,
          wqkvS[nsel], w1S[nsel], w2S[nsel], 0,
          cs, Wm + (size_t)(l + 1) * 6291456, bm + (l + 1) * 6144,
          mAll + (size_t)(l + 1) * 49152);
    } else {
      k_attn<<<dim3(29, 128), 256, 0, stream>>>(qb, kb, vb, cntb, att,
          Wf, Wf, Wf, Wf, Wf, wfb, wfb, wfb, 1,
          cs, nullptr, nullptr, nullptr);
    }
    k_resid<<<4096, 256, 0, stream>>>(x, att, m6b, cntb, strtb, t2bb, h);
    k_gemm<1, 128, 64><<<dim3(64, 32), 256, 0, stream>>>(h, w1S[sel], b1 + l * 4096, 1024, 1024, 4096,
                                                         cntb, strtb, t2bb, f1, nullptr);
    k_gemm<4, 128, 128><<<dim3(8, 32, 8), 256, 0, stream>>>(f1, w2S[sel], nullptr, 4096, 512, 1024,
                                                            cntb, strtb, t2bb, part, nullptr);
    const float* nShift = last ? m2v : (mAll + (size_t)(l + 1) * 49152);
    const float* nScale = last ? (m2v + 1024) : (mAll + (size_t)(l + 1) * 49152 + 1024);
    int nStride = last ? 2048 : 6144;
    k_comb<<<4096, 256, 0, stream>>>(part, b2 + l * 1024, m6b + 5120,
                                     nShift, nScale, nStride,
                                     x, cntb, strtb, t2bb, h);
  }

  k_gemm<3, 128, 64><<<dim3(16, 32), 256, 0, stream>>>(h, wfb, bfp, 1024, 1024, 1024,
                                                       cntb, strtb, t2bb, nullptr, ffin);
  k_scatter<<<4096, 256, 0, stream>>>(ffin, posb, strtb, (float*)d_out);
}